// Round 6
// baseline (1310.482 us; speedup 1.0000x reference)
//
#include <hip/hip_runtime.h>
#include <math.h>

// ODE-RNN persistent kernel, round 17: R16 int8 body + PINNED VGPR budget.
// R16 post-mortem (root cause of R13/R14/R16 failures): __launch_bounds__
// (1024,4) only sets a MINIMUM waves/EU; the allocator targeted 8 waves/
// SIMD = 64-VGPR budget in every round (VGPR_Count=64 throughout) and
// spilled whatever we hoisted. R16's extra 8 live acc regs (accQ+accX)
// pushed w1f/w2f to scratch: FETCH 16MB -> 3.06GB (= 117 B/thr/step, the
// fragment set), dur 796 -> 1155us. Measured occupancy (~46%) shows the
// 2nd block/CU never materialized anyway -- the 64-VGPR price bought
// nothing. Fix: amdgpu_waves_per_eu(4,4) pins exactly 4 waves/SIMD =
// 16 waves/CU = our one persistent block -> 128-VGPR budget, no spill.
// Body byte-identical to R16 (int8 Whh stream: 576->320 KB/WG/step;
// absmax 0.00195 = 2 fp16 quanta, validated). Euler kept: 5 syncs/step.

#define NWG  256
#define NTHR 1024
#define Tn   100
#define Dn   64
#define Hn   512
#define Fn   50
#define YP   528   // fp16 pitch: 264 dwords == 8 mod 32 -> A-reads 2-way max
#define YQP  544   // i8 pitch: 136 dwords == 8 mod 32 -> uniform bank spread
#define XP   80
#define GPp  80
#define GPI  17
#define SB_WHH 2873.682f              // 127 / (1/sqrt(512))
#define QDH (1.0f/(125.0f*SB_WHH))    // dequant: (1/sA)*(1/sB)

typedef __attribute__((ext_vector_type(8))) _Float16 half8;
typedef __attribute__((ext_vector_type(4))) float f32x4;
typedef __attribute__((ext_vector_type(4))) int   i32x4;

__device__ __forceinline__ float my_tanh(float v) {
    float e = __expf(2.0f * v);
    return 1.0f - 2.0f / (e + 1.0f);   // exact 0 at v=0
}
__device__ __forceinline__ float wave_red(float v) {
#pragma unroll
    for (int o = 32; o > 0; o >>= 1) v += __shfl_down(v, o);
    return v;
}

// f(y) = tanh(tanh(y@W1^T + b1)@W2^T + b2) * scale_row. Two internal syncs.
// Wave w: GEMM1 job (kh=w>>2, nt1=w&3, 4 MFMA, B in w1f); GEMM2 n-tiles
// {w, w+16} (B in w2f). kout[i][r] valid in lanes<16.
__device__ __forceinline__ void feval(
    const _Float16* arg, const half8 w1f[4], const half8 w2f[2][2],
    float* gp, _Float16* gbf, const float b1v, const float b2v[2],
    const float scr[4], int w, int lane, int tid, float kout[2][4])
{
    const int m4 = lane & 3, q = (lane >> 4) & 3;
    const int kh = w >> 2;
    f32x4 acc = {0.f, 0.f, 0.f, 0.f};
    const _Float16* arow = arg + m4 * YP + q * 8;
#pragma unroll
    for (int t = 0; t < 4; ++t) {
        half8 a = *(const half8*)(arow + (kh * 4 + t) * 32);
        acc = __builtin_amdgcn_mfma_f32_16x16x32_f16(a, w1f[t], acc, 0, 0, 0);
    }
    if (lane < 16) {
#pragma unroll
        for (int r = 0; r < 4; ++r)
            gp[(w * 4 + r) * GPI + lane] = acc[r];
    }
    __syncthreads();
    if (tid < 256) {   // mid layer once: 4 rows x 64 neurons
        const int r = tid >> 6, n = tid & 63;
        const int nt = n >> 4, c = n & 15;
        float s = gp[((0*4 + nt) * 4 + r) * GPI + c]
                + gp[((1*4 + nt) * 4 + r) * GPI + c]
                + gp[((2*4 + nt) * 4 + r) * GPI + c]
                + gp[((3*4 + nt) * 4 + r) * GPI + c];
        float g = (n < Fn) ? my_tanh(s + b1v) : 0.0f;
        gbf[r * GPp + n] = (_Float16)g;
    }
    __syncthreads();
    half8 af0 = *(const half8*)(gbf + m4 * GPp + q * 8);
    half8 af1 = *(const half8*)(gbf + m4 * GPp + 32 + q * 8);
#pragma unroll
    for (int i = 0; i < 2; ++i) {
        f32x4 c = {0.f, 0.f, 0.f, 0.f};
        c = __builtin_amdgcn_mfma_f32_16x16x32_f16(af0, w2f[i][0], c, 0, 0, 0);
        c = __builtin_amdgcn_mfma_f32_16x16x32_f16(af1, w2f[i][1], c, 0, 0, 0);
        if (lane < 16) {
#pragma unroll
            for (int r = 0; r < 4; ++r)
                kout[i][r] = my_tanh(c[r] + b2v[i]) * scr[r];
        }
    }
}

extern "C" __global__ void __launch_bounds__(NTHR)
__attribute__((amdgpu_waves_per_eu(4, 4)))
odernn_main(const float* __restrict__ dt, const float* __restrict__ x,
            const float* __restrict__ b_ih, const float* __restrict__ b_hh,
            const float* __restrict__ b1,   const float* __restrict__ b2,
            const float* __restrict__ bl1,  const float* __restrict__ Wmu,
            const float* __restrict__ bmu,
            const _Float16* __restrict__ w1p,  const _Float16* __restrict__ w2p,
            const signed char* __restrict__ whh8, const _Float16* __restrict__ wih,
            const _Float16* __restrict__ wl1p,
            _Float16* __restrict__ yg, float* __restrict__ out, int defer)
{
    __shared__ __align__(16) _Float16 ybuf[4*YP];
    __shared__ __align__(16) signed char ybq[4*YQP];
    __shared__ __align__(16) _Float16 xbuf[4*XP];
    __shared__ __align__(16) _Float16 gbf[4*GPp];
    __shared__ __align__(16) float    gp[64*GPI];
    __shared__ float sc_row[4], hp[64];

    const int tid  = threadIdx.x;
    const int w    = tid >> 6;       // wave 0..15
    const int lane = tid & 63;
    const int m4   = lane & 3, q = (lane >> 4) & 3;
    const int cw   = lane & 15;
    const int row0 = blockIdx.x * 4;

    for (int i = tid; i < 4*YP;  i += NTHR) ybuf[i] = (_Float16)0.0f;
    for (int i = tid; i < 4*YQP; i += NTHR) ybq[i]  = 0;

    // hoisted loop-invariant f-net B-fragments (32 VGPRs)
    half8 w1f[4];
    {
        const int kh = w >> 2, nt1 = w & 3;
#pragma unroll
        for (int t = 0; t < 4; ++t) {
            const int kt = kh * 4 + t;
            w1f[t] = ((const half8*)w1p)[(((kt << 2) + nt1) << 6) + lane];
        }
    }
    half8 w2f[2][2];
#pragma unroll
    for (int i = 0; i < 2; ++i) {
        const int nt = w + (i << 4);
        w2f[i][0] = ((const half8*)w2p)[(nt << 6) + lane];
        w2f[i][1] = ((const half8*)w2p)[((32 + nt) << 6) + lane];
    }

    float bC[2], b2v[2];
    int ci[2];
#pragma unroll
    for (int i = 0; i < 2; ++i) {
        const int n = (w + i*16)*16 + cw;
        bC[i]  = b_ih[n] + b_hh[n];
        b2v[i] = b2[n];
        ci[i]  = n;
    }
    const float b1v = (tid < 256 && (tid & 63) < Fn) ? b1[tid & 63] : 0.0f;
    const float blv = bl1[w*16 + cw];   // fallback head only
    const float wmv = Wmu[w*16 + cw];
    const float bmu0 = bmu[0];

    float ycur[2][4];
    float k1[2][4];
    float scr[4];
    float xv = 0.f, scn = 0.f;

    // stage x/sc for ts = 0
    if (tid < 256) {
        const int r = tid >> 6, c = tid & 63;
        xbuf[r*XP + c] = (_Float16)x[((size_t)(row0 + r)*Tn + 0)*Dn + c];
    }
    if (tid < 4) {
        const size_t di = ((size_t)(row0 + tid)*Tn + 0)*2;
        sc_row[tid] = (dt[di + 1] - dt[di]) * 0.01f;
    }
    __syncthreads();

#pragma unroll 1
    for (int ts = 0; ts < Tn; ++ts) {
#pragma unroll
        for (int r = 0; r < 4; ++r) scr[r] = sc_row[r];

        // ---- RNN cell: h@Whh in int8 MFMA (K=64, 8 kt x 2 n-tiles,
        //      256 KB/WG/step streamed); x@Wih in fp16 (64 KB/step) ----
        i32x4 accQ0 = {0,0,0,0};
        i32x4 accQ1 = {0,0,0,0};
        {
            const signed char* yq = ybq + m4*YQP + q*16;
#pragma unroll
            for (int kt = 0; kt < 8; ++kt) {
                i32x4 a = *(const i32x4*)(yq + kt*64);
                i32x4 b0 = *(const i32x4*)(whh8 + (((kt*32 + w)      << 10) + (lane << 4)));
                i32x4 b1h= *(const i32x4*)(whh8 + (((kt*32 + w + 16) << 10) + (lane << 4)));
                accQ0 = __builtin_amdgcn_mfma_i32_16x16x64_i8(a, b0,  accQ0, 0,0,0);
                accQ1 = __builtin_amdgcn_mfma_i32_16x16x64_i8(a, b1h, accQ1, 0,0,0);
            }
        }
        f32x4 accX0 = {0.f,0.f,0.f,0.f};
        f32x4 accX1 = {0.f,0.f,0.f,0.f};
        {
            const _Float16* xh = xbuf + m4*XP + q*8;
#pragma unroll
            for (int kt = 0; kt < 2; ++kt) {
                half8 ah = *(const half8*)(xh + kt*32);
                half8 bw0 = *(const half8*)(wih + (((kt*32 + w)      << 9) + (lane << 3)));
                half8 bw1 = *(const half8*)(wih + (((kt*32 + w + 16) << 9) + (lane << 3)));
                accX0 = __builtin_amdgcn_mfma_f32_16x16x32_f16(ah, bw0, accX0, 0,0,0);
                accX1 = __builtin_amdgcn_mfma_f32_16x16x32_f16(ah, bw1, accX1, 0,0,0);
            }
        }
        __syncthreads();   // S1: all A-reads of old ybuf/ybq/xbuf done
        if (lane < 16) {
#pragma unroll
            for (int r = 0; r < 4; ++r) {
                float pre0 = (float)accQ0[r] * QDH + accX0[r] + bC[0];
                ycur[0][r] = my_tanh(pre0);
                ybuf[r*YP + ci[0]] = (_Float16)ycur[0][r];
                ybq[r*YQP + ci[0]] = (signed char)(int)rintf(ycur[0][r] * 125.0f);
                float pre1 = (float)accQ1[r] * QDH + accX1[r] + bC[1];
                ycur[1][r] = my_tanh(pre1);
                ybuf[r*YP + ci[1]] = (_Float16)ycur[1][r];
                ybq[r*YQP + ci[1]] = (signed char)(int)rintf(ycur[1][r] * 125.0f);
            }
        }
        // prefetch x/dt for next step (lands during feval)
        {
            const int tsn = (ts + 1 < Tn) ? ts + 1 : ts;
            if (tid < 256) {
                const int r = tid >> 6, c = tid & 63;
                xv = x[((size_t)(row0 + r)*Tn + tsn)*Dn + c];
            }
            if (tid < 4) {
                const size_t di = ((size_t)(row0 + tid)*Tn + tsn)*2;
                scn = (dt[di + 1] - dt[di]) * 0.01f;
            }
        }
        __syncthreads();   // S2: y0 visible

        // ---- ODE: Euler step, h = 1 (feval has 2 syncs: S3, S4) ----
        feval(ybuf, w1f, w2f, gp, gbf, b1v, b2v, scr, w, lane, tid, k1);

        // y_new = y + k1; stage next x/sc
        if (lane < 16) {
#pragma unroll
            for (int i = 0; i < 2; ++i)
#pragma unroll
                for (int r = 0; r < 4; ++r) {
                    ycur[i][r] += k1[i][r];
                    ybuf[r*YP + ci[i]] = (_Float16)ycur[i][r];
                    ybq[r*YQP + ci[i]] =
                        (signed char)(int)rintf(ycur[i][r] * 125.0f);
                }
        }
        if (tid < 256) xbuf[(tid >> 6)*XP + (tid & 63)] = (_Float16)xv;
        if (tid < 4)   sc_row[tid] = scn;
        __syncthreads();   // S5: ynew + x + sc visible

        if (defer) {
            // store y (fp16) for phase-2 head; coalesced dword per thread
            const int r = tid >> 8, c = (tid & 255) * 2;
            unsigned u = *(const unsigned*)(ybuf + r*YP + c);
            *(unsigned*)(yg + (((size_t)(row0 + r)*Tn + ts)*512 + c)) = u;
        } else {
            // in-loop head (fallback)
            f32x4 aH = {0.f,0.f,0.f,0.f};
            const _Float16* yh = ybuf + m4*YP + q*8;
#pragma unroll 4
            for (int kt = 0; kt < 16; ++kt) {
                half8 ah = *(const half8*)(yh + kt*32);
                half8 b = *(const half8*)(wl1p + ((kt*16 + w) << 9) + (lane << 3));
                aH = __builtin_amdgcn_mfma_f32_16x16x32_f16(ah, b, aH, 0,0,0);
            }
            float pr[4];
#pragma unroll
            for (int r = 0; r < 4; ++r) {
                float p = (lane < 16) ? fmaxf(aH[r] + blv, 0.0f) * wmv : 0.0f;
                pr[r] = wave_red(p);
            }
            if (lane == 0) {
#pragma unroll
                for (int r = 0; r < 4; ++r) hp[w*4 + r] = pr[r];
            }
            __syncthreads();
            if (tid < 4) {
                float s = bmu0;
#pragma unroll
                for (int wv = 0; wv < 16; ++wv) s += hp[wv*4 + tid];
                out[(size_t)(row0 + tid)*Tn + ts] = s;
            }
            __syncthreads();
        }
    }
}

// phase-2 head: out[b,t] = relu(y[b,t]@Wl1^T + bl1)@Wmu^T + bmu
// grid = (B/16)*Tn WGs x 256 threads; wave w covers n in [w*64,(w+1)*64)
extern "C" __global__ void __launch_bounds__(256, 4)
odernn_head(const _Float16* __restrict__ yg, const _Float16* __restrict__ wl1p,
            const float* __restrict__ bl1, const float* __restrict__ Wmu,
            const float* __restrict__ bmu, float* __restrict__ out)
{
    __shared__ float hp[4][16];
    const int tid = threadIdx.x, w = tid >> 6, lane = tid & 63;
    const int q = (lane >> 4) & 3;
    const int b0 = (blockIdx.x / Tn) * 16, ts = blockIdx.x % Tn;

    f32x4 acc[4];
#pragma unroll
    for (int j = 0; j < 4; ++j) acc[j] = (f32x4){0.f,0.f,0.f,0.f};
    const _Float16* ap = yg + ((size_t)(b0 + (lane & 15))*Tn + ts)*512 + q*8;
#pragma unroll 4
    for (int kt = 0; kt < 16; ++kt) {
        half8 a = *(const half8*)(ap + kt*32);
#pragma unroll
        for (int j = 0; j < 4; ++j) {
            half8 b = *(const half8*)(wl1p + ((kt*16 + w*4 + j) << 9) + (lane << 3));
            acc[j] = __builtin_amdgcn_mfma_f32_16x16x32_f16(a, b, acc[j], 0,0,0);
        }
    }
    float pr[4] = {0.f, 0.f, 0.f, 0.f};
#pragma unroll
    for (int j = 0; j < 4; ++j) {
        const int n = (w*4 + j)*16 + (lane & 15);
        const float blv = bl1[n], wmv = Wmu[n];
#pragma unroll
        for (int r = 0; r < 4; ++r)
            pr[r] += fmaxf(acc[j][r] + blv, 0.0f) * wmv;
    }
#pragma unroll
    for (int r = 0; r < 4; ++r)
#pragma unroll
        for (int o = 1; o < 16; o <<= 1) pr[r] += __shfl_xor(pr[r], o);
    if ((lane & 15) == 0) {
        const int g = lane >> 4;
#pragma unroll
        for (int r = 0; r < 4; ++r) hp[w][g*4 + r] = pr[r];
    }
    __syncthreads();
    if (tid < 16)
        out[(size_t)(b0 + tid)*Tn + ts] =
            hp[0][tid] + hp[1][tid] + hp[2][tid] + hp[3][tid] + bmu[0];
}

// pack weights: fp16 MFMA B-fragment order (B[k][n] = W[n][k]) for the
// f-net / wih / wl1; int8 B-fragment order (K=64) for Whh.
extern "C" __global__ void odernn_init(
    const float* __restrict__ W_ih, const float* __restrict__ W_hh,
    const float* __restrict__ W1,   const float* __restrict__ W2,
    const float* __restrict__ Wl1,
    _Float16* w1p, _Float16* w2p, signed char* whh8, _Float16* wih,
    _Float16* wl1p)
{
    const int idx = blockIdx.x * blockDim.x + threadIdx.x;
    const int stride = gridDim.x * blockDim.x;
    // W1: KT=16, NT=4 (N 50->64), K=512
    for (int p = idx; p < 32768; p += stride) {
        int j = p & 7, lane = (p >> 3) & 63, t = p >> 9;
        int nt = t & 3, kt = t >> 2;
        int n = nt*16 + (lane & 15), k = kt*32 + ((lane >> 4) << 3) + j;
        w1p[p] = (_Float16)((n < 50) ? W1[n*512 + k] : 0.f);
    }
    // W2: KT=2 (K 50->64), NT=32, N=512
    for (int p = idx; p < 32768; p += stride) {
        int j = p & 7, lane = (p >> 3) & 63, t = p >> 9;
        int nt = t & 31, kt = t >> 5;
        int n = nt*16 + (lane & 15), k = kt*32 + ((lane >> 4) << 3) + j;
        w2p[p] = (_Float16)((k < 50) ? W2[n*50 + k] : 0.f);
    }
    // Whh int8: KT=8 (K=64 each), NT=32; B frag: 16 bytes/lane,
    // n = nt*16+(lane&15), k = kt*64 + (lane>>4)*16 + j
    for (int p = idx; p < 262144; p += stride) {
        int j = p & 15, lane = (p >> 4) & 63, t = p >> 10;
        int nt = t & 31, kt = t >> 5;
        int n = nt*16 + (lane & 15), k = kt*64 + ((lane >> 4) << 4) + j;
        float v = rintf(W_hh[n*512 + k] * SB_WHH);
        v = fminf(127.0f, fmaxf(-127.0f, v));
        whh8[p] = (signed char)(int)v;
    }
    // Wih: KT=2, NT=32, K=64 (fp16)
    for (int p = idx; p < 32768; p += stride) {
        int j = p & 7, lane = (p >> 3) & 63, t = p >> 9;
        int nt = t & 31, kt = t >> 5;
        int n = nt*16 + (lane & 15), k = kt*32 + ((lane >> 4) << 3) + j;
        wih[p] = (_Float16)W_ih[n*64 + k];
    }
    // Wl1: KT=16, NT=16, N=256, K=512
    for (int p = idx; p < 131072; p += stride) {
        int j = p & 7, lane = (p >> 3) & 63, t = p >> 9;
        int nt = t & 15, kt = t >> 4;
        int n = nt*16 + (lane & 15), k = kt*32 + ((lane >> 4) << 3) + j;
        wl1p[p] = (_Float16)Wl1[n*512 + k];
    }
}

extern "C" void kernel_launch(void* const* d_in, const int* in_sizes, int n_in,
                              void* d_out, int out_size, void* d_ws, size_t ws_size,
                              hipStream_t stream)
{
    (void)in_sizes; (void)n_in; (void)out_size;
    const float* dt   = (const float*)d_in[0];
    const float* x    = (const float*)d_in[1];
    const float* W_ih = (const float*)d_in[2];
    const float* b_ih = (const float*)d_in[3];
    const float* W_hh = (const float*)d_in[4];
    const float* b_hh = (const float*)d_in[5];
    const float* W1   = (const float*)d_in[6];
    const float* b1   = (const float*)d_in[7];
    const float* W2   = (const float*)d_in[8];
    const float* b2   = (const float*)d_in[9];
    const float* Wl1  = (const float*)d_in[10];
    const float* bl1  = (const float*)d_in[11];
    const float* Wmu  = (const float*)d_in[12];
    const float* bmu  = (const float*)d_in[13];
    float* out = (float*)d_out;

    char* ws = (char*)d_ws;
    _Float16*    w1p  = (_Float16*)(ws);             // 64 KB
    _Float16*    w2p  = (_Float16*)(ws + 65536);     // 64 KB
    signed char* whh8 = (signed char*)(ws + 131072); // 256 KB (of 512 KB slot)
    _Float16*    wih  = (_Float16*)(ws + 655360);    // 64 KB
    _Float16*    wl1p = (_Float16*)(ws + 720896);    // 256 KB
    _Float16*    yg   = (_Float16*)(ws + 1048576);   // 105 MB (if available)

    const size_t need = 1048576 + (size_t)1024 * Tn * 512 * sizeof(_Float16);
    const int defer = (ws_size >= need) ? 1 : 0;

    odernn_init<<<256, 256, 0, stream>>>(W_ih, W_hh, W1, W2, Wl1,
                                         w1p, w2p, whh8, wih, wl1p);
    odernn_main<<<NWG, NTHR, 0, stream>>>(dt, x, b_ih, b_hh, b1, b2, bl1, Wmu, bmu,
                                          w1p, w2p, whh8, wih, wl1p,
                                          yg, out, defer);
    if (defer)
        odernn_head<<<(1024/16)*Tn, 256, 0, stream>>>(yg, wl1p, bl1, Wmu, bmu, out);
}

// Round 7
// 1085.188 us; speedup vs baseline: 1.2076x; 1.2076x over previous
//
#include <hip/hip_runtime.h>
#include <math.h>

// ODE-RNN persistent kernel, round 18: int8 Whh stream INSIDE 64 VGPRs.
// R16/R17 post-mortem: the allocator's effective budget is 64 arch VGPRs
// regardless of launch_bounds/waves_per_eu (6 rounds of evidence); R16's
// extra accX pair (8 regs) pushed w1f/w2f to scratch -> FETCH 3.06 GB
// (= 128 B/thr/step), dur 1155us. R18 keeps R16's int8 math but cuts 20
// regs of live range: (1) x@Wih MFMA runs FIRST, result+bias parked in
// LDS bcx (8 KB, same-thread across existing S1 barrier; sched_barrier
// pins the phase so accX dies before the int8 loop); (2) ycur dropped --
// y0 re-read from fp16 ybuf after feval (<=1 quantum/step drift);
// (3) scr[4] regs -> direct sc_row LDS reads in feval. Peak demand now
// strictly below R11's proven 64-reg profile. Stream: 576->320 KB/WG/step
// through XCD-L2 (the R16 win, now unburied). Euler kept: 5 syncs/step.

#define NWG  256
#define NTHR 1024
#define Tn   100
#define Dn   64
#define Hn   512
#define Fn   50
#define YP   528   // fp16 pitch: 264 dwords == 8 mod 32 -> A-reads 2-way max
#define YQP  544   // i8 pitch: 136 dwords == 8 mod 32 -> uniform bank spread
#define XP   80
#define GPp  80
#define GPI  17
#define BXP  516   // bcx pitch (dwords): 16-lane consecutive access, no conflict
#define SB_WHH 2873.682f              // 127 / (1/sqrt(512))
#define QDH (1.0f/(125.0f*SB_WHH))    // dequant: (1/sA)*(1/sB)

typedef __attribute__((ext_vector_type(8))) _Float16 half8;
typedef __attribute__((ext_vector_type(4))) float f32x4;
typedef __attribute__((ext_vector_type(4))) int   i32x4;

__device__ __forceinline__ float my_tanh(float v) {
    float e = __expf(2.0f * v);
    return 1.0f - 2.0f / (e + 1.0f);   // exact 0 at v=0
}
__device__ __forceinline__ float wave_red(float v) {
#pragma unroll
    for (int o = 32; o > 0; o >>= 1) v += __shfl_down(v, o);
    return v;
}
__device__ __forceinline__ signed char q125(float v) {
    return (signed char)(int)rintf(v * 125.0f);
}

// f(y) = tanh(tanh(y@W1^T + b1)@W2^T + b2) * sc_row[r]. Two internal syncs.
// Wave w: GEMM1 job (kh=w>>2, nt1=w&3, 4 MFMA, B in w1f); GEMM2 n-tiles
// {w, w+16} (B in w2f). kout[i][r] valid in lanes<16.
__device__ __forceinline__ void feval(
    const _Float16* arg, const half8 w1f[4], const half8 w2f[2][2],
    float* gp, _Float16* gbf, const float b1v, const float b2v[2],
    const float* sc_row, int w, int lane, int tid, float kout[2][4])
{
    const int m4 = lane & 3, q = (lane >> 4) & 3;
    const int kh = w >> 2;
    f32x4 acc = {0.f, 0.f, 0.f, 0.f};
    const _Float16* arow = arg + m4 * YP + q * 8;
#pragma unroll
    for (int t = 0; t < 4; ++t) {
        half8 a = *(const half8*)(arow + (kh * 4 + t) * 32);
        acc = __builtin_amdgcn_mfma_f32_16x16x32_f16(a, w1f[t], acc, 0, 0, 0);
    }
    if (lane < 16) {
#pragma unroll
        for (int r = 0; r < 4; ++r)
            gp[(w * 4 + r) * GPI + lane] = acc[r];
    }
    __syncthreads();
    if (tid < 256) {   // mid layer once: 4 rows x 64 neurons
        const int r = tid >> 6, n = tid & 63;
        const int nt = n >> 4, c = n & 15;
        float s = gp[((0*4 + nt) * 4 + r) * GPI + c]
                + gp[((1*4 + nt) * 4 + r) * GPI + c]
                + gp[((2*4 + nt) * 4 + r) * GPI + c]
                + gp[((3*4 + nt) * 4 + r) * GPI + c];
        float g = (n < Fn) ? my_tanh(s + b1v) : 0.0f;
        gbf[r * GPp + n] = (_Float16)g;
    }
    __syncthreads();
    half8 af0 = *(const half8*)(gbf + m4 * GPp + q * 8);
    half8 af1 = *(const half8*)(gbf + m4 * GPp + 32 + q * 8);
#pragma unroll
    for (int i = 0; i < 2; ++i) {
        f32x4 c = {0.f, 0.f, 0.f, 0.f};
        c = __builtin_amdgcn_mfma_f32_16x16x32_f16(af0, w2f[i][0], c, 0, 0, 0);
        c = __builtin_amdgcn_mfma_f32_16x16x32_f16(af1, w2f[i][1], c, 0, 0, 0);
        if (lane < 16) {
#pragma unroll
            for (int r = 0; r < 4; ++r)
                kout[i][r] = my_tanh(c[r] + b2v[i]) * sc_row[r];
        }
    }
}

extern "C" __global__ void __launch_bounds__(NTHR, 4)
odernn_main(const float* __restrict__ dt, const float* __restrict__ x,
            const float* __restrict__ b_ih, const float* __restrict__ b_hh,
            const float* __restrict__ b1,   const float* __restrict__ b2,
            const float* __restrict__ bl1,  const float* __restrict__ Wmu,
            const float* __restrict__ bmu,
            const _Float16* __restrict__ w1p,  const _Float16* __restrict__ w2p,
            const signed char* __restrict__ whh8, const _Float16* __restrict__ wih,
            const _Float16* __restrict__ wl1p,
            _Float16* __restrict__ yg, float* __restrict__ out, int defer)
{
    __shared__ __align__(16) _Float16 ybuf[4*YP];
    __shared__ __align__(16) signed char ybq[4*YQP];
    __shared__ __align__(16) _Float16 xbuf[4*XP];
    __shared__ __align__(16) _Float16 gbf[4*GPp];
    __shared__ __align__(16) float    gp[64*GPI];
    __shared__ __align__(16) float    bcx[4*BXP];
    __shared__ float sc_row[4], hp[64];

    const int tid  = threadIdx.x;
    const int w    = tid >> 6;       // wave 0..15
    const int lane = tid & 63;
    const int m4   = lane & 3, q = (lane >> 4) & 3;
    const int cw   = lane & 15;
    const int row0 = blockIdx.x * 4;

    for (int i = tid; i < 4*YP;  i += NTHR) ybuf[i] = (_Float16)0.0f;
    for (int i = tid; i < 4*YQP; i += NTHR) ybq[i]  = 0;

    // hoisted loop-invariant f-net B-fragments (32 VGPRs -- R11-proven fit)
    half8 w1f[4];
    {
        const int kh = w >> 2, nt1 = w & 3;
#pragma unroll
        for (int t = 0; t < 4; ++t) {
            const int kt = kh * 4 + t;
            w1f[t] = ((const half8*)w1p)[(((kt << 2) + nt1) << 6) + lane];
        }
    }
    half8 w2f[2][2];
#pragma unroll
    for (int i = 0; i < 2; ++i) {
        const int nt = w + (i << 4);
        w2f[i][0] = ((const half8*)w2p)[(nt << 6) + lane];
        w2f[i][1] = ((const half8*)w2p)[((32 + nt) << 6) + lane];
    }

    float bC[2], b2v[2];
    int ci[2];
#pragma unroll
    for (int i = 0; i < 2; ++i) {
        const int n = (w + i*16)*16 + cw;
        bC[i]  = b_ih[n] + b_hh[n];
        b2v[i] = b2[n];
        ci[i]  = n;
    }
    const float b1v = (tid < 256 && (tid & 63) < Fn) ? b1[tid & 63] : 0.0f;
    const float blv = bl1[w*16 + cw];   // fallback head only
    const float wmv = Wmu[w*16 + cw];
    const float bmu0 = bmu[0];

    float k1[2][4];
    float xv = 0.f, scn = 0.f;

    // stage x/sc for ts = 0
    if (tid < 256) {
        const int r = tid >> 6, c = tid & 63;
        xbuf[r*XP + c] = (_Float16)x[((size_t)(row0 + r)*Tn + 0)*Dn + c];
    }
    if (tid < 4) {
        const size_t di = ((size_t)(row0 + tid)*Tn + 0)*2;
        sc_row[tid] = (dt[di + 1] - dt[di]) * 0.01f;
    }
    __syncthreads();

#pragma unroll 1
    for (int ts = 0; ts < Tn; ++ts) {
        // ---- Phase A: x@Wih (fp16 MFMA) + bias -> LDS bcx; accX dies here ----
        {
            f32x4 accX0 = {0.f,0.f,0.f,0.f};
            f32x4 accX1 = {0.f,0.f,0.f,0.f};
            const _Float16* xh = xbuf + m4*XP + q*8;
#pragma unroll
            for (int kt = 0; kt < 2; ++kt) {
                half8 ah = *(const half8*)(xh + kt*32);
                half8 bw0 = *(const half8*)(wih + (((kt*32 + w)      << 9) + (lane << 3)));
                half8 bw1 = *(const half8*)(wih + (((kt*32 + w + 16) << 9) + (lane << 3)));
                accX0 = __builtin_amdgcn_mfma_f32_16x16x32_f16(ah, bw0, accX0, 0,0,0);
                accX1 = __builtin_amdgcn_mfma_f32_16x16x32_f16(ah, bw1, accX1, 0,0,0);
            }
            if (lane < 16) {
#pragma unroll
                for (int r = 0; r < 4; ++r) {
                    bcx[r*BXP + ci[0]] = accX0[r] + bC[0];
                    bcx[r*BXP + ci[1]] = accX1[r] + bC[1];
                }
            }
        }
        __builtin_amdgcn_sched_barrier(0);   // pin phase: accX must die here

        // ---- Phase B: h@Whh int8 MFMA (K=64, 8 kt x 2 n-tiles, 256 KB/step) ----
        i32x4 accQ0 = {0,0,0,0};
        i32x4 accQ1 = {0,0,0,0};
        {
            const signed char* yq = ybq + m4*YQP + q*16;
#pragma unroll
            for (int kt = 0; kt < 8; ++kt) {
                i32x4 a = *(const i32x4*)(yq + kt*64);
                i32x4 b0 = *(const i32x4*)(whh8 + (((kt*32 + w)      << 10) + (lane << 4)));
                i32x4 b1h= *(const i32x4*)(whh8 + (((kt*32 + w + 16) << 10) + (lane << 4)));
                accQ0 = __builtin_amdgcn_mfma_i32_16x16x64_i8(a, b0,  accQ0, 0,0,0);
                accQ1 = __builtin_amdgcn_mfma_i32_16x16x64_i8(a, b1h, accQ1, 0,0,0);
            }
        }
        __syncthreads();   // S1: all A-reads of old ybq/xbuf done; bcx visible
        if (lane < 16) {
#pragma unroll
            for (int r = 0; r < 4; ++r) {
                float y0a = my_tanh((float)accQ0[r] * QDH + bcx[r*BXP + ci[0]]);
                ybuf[r*YP + ci[0]] = (_Float16)y0a;
                ybq[r*YQP + ci[0]] = q125(y0a);
                float y0b = my_tanh((float)accQ1[r] * QDH + bcx[r*BXP + ci[1]]);
                ybuf[r*YP + ci[1]] = (_Float16)y0b;
                ybq[r*YQP + ci[1]] = q125(y0b);
            }
        }
        // prefetch x/dt for next step (lands during feval)
        {
            const int tsn = (ts + 1 < Tn) ? ts + 1 : ts;
            if (tid < 256) {
                const int r = tid >> 6, c = tid & 63;
                xv = x[((size_t)(row0 + r)*Tn + tsn)*Dn + c];
            }
            if (tid < 4) {
                const size_t di = ((size_t)(row0 + tid)*Tn + tsn)*2;
                scn = (dt[di + 1] - dt[di]) * 0.01f;
            }
        }
        __syncthreads();   // S2: y0 visible

        // ---- ODE: Euler step, h = 1 (feval has 2 syncs: S3, S4) ----
        feval(ybuf, w1f, w2f, gp, gbf, b1v, b2v, sc_row, w, lane, tid, k1);

        // y_new = y0 (re-read fp16) + k1; stage next x/sc
        if (lane < 16) {
#pragma unroll
            for (int i = 0; i < 2; ++i)
#pragma unroll
                for (int r = 0; r < 4; ++r) {
                    float yn = (float)ybuf[r*YP + ci[i]] + k1[i][r];
                    ybuf[r*YP + ci[i]] = (_Float16)yn;
                    ybq[r*YQP + ci[i]] = q125(yn);
                }
        }
        if (tid < 256) xbuf[(tid >> 6)*XP + (tid & 63)] = (_Float16)xv;
        if (tid < 4)   sc_row[tid] = scn;
        __syncthreads();   // S5: ynew + x + sc visible

        if (defer) {
            // store y (fp16) for phase-2 head; coalesced dword per thread
            const int r = tid >> 8, c = (tid & 255) * 2;
            unsigned u = *(const unsigned*)(ybuf + r*YP + c);
            *(unsigned*)(yg + (((size_t)(row0 + r)*Tn + ts)*512 + c)) = u;
        } else {
            // in-loop head (fallback)
            f32x4 aH = {0.f,0.f,0.f,0.f};
            const _Float16* yh = ybuf + m4*YP + q*8;
#pragma unroll 4
            for (int kt = 0; kt < 16; ++kt) {
                half8 ah = *(const half8*)(yh + kt*32);
                half8 b = *(const half8*)(wl1p + ((kt*16 + w) << 9) + (lane << 3));
                aH = __builtin_amdgcn_mfma_f32_16x16x32_f16(ah, b, aH, 0,0,0);
            }
            float pr[4];
#pragma unroll
            for (int r = 0; r < 4; ++r) {
                float p = (lane < 16) ? fmaxf(aH[r] + blv, 0.0f) * wmv : 0.0f;
                pr[r] = wave_red(p);
            }
            if (lane == 0) {
#pragma unroll
                for (int r = 0; r < 4; ++r) hp[w*4 + r] = pr[r];
            }
            __syncthreads();
            if (tid < 4) {
                float s = bmu0;
#pragma unroll
                for (int wv = 0; wv < 16; ++wv) s += hp[wv*4 + tid];
                out[(size_t)(row0 + tid)*Tn + ts] = s;
            }
            __syncthreads();
        }
    }
}

// phase-2 head: out[b,t] = relu(y[b,t]@Wl1^T + bl1)@Wmu^T + bmu
// grid = (B/16)*Tn WGs x 256 threads; wave w covers n in [w*64,(w+1)*64)
extern "C" __global__ void __launch_bounds__(256, 4)
odernn_head(const _Float16* __restrict__ yg, const _Float16* __restrict__ wl1p,
            const float* __restrict__ bl1, const float* __restrict__ Wmu,
            const float* __restrict__ bmu, float* __restrict__ out)
{
    __shared__ float hp[4][16];
    const int tid = threadIdx.x, w = tid >> 6, lane = tid & 63;
    const int q = (lane >> 4) & 3;
    const int b0 = (blockIdx.x / Tn) * 16, ts = blockIdx.x % Tn;

    f32x4 acc[4];
#pragma unroll
    for (int j = 0; j < 4; ++j) acc[j] = (f32x4){0.f,0.f,0.f,0.f};
    const _Float16* ap = yg + ((size_t)(b0 + (lane & 15))*Tn + ts)*512 + q*8;
#pragma unroll 4
    for (int kt = 0; kt < 16; ++kt) {
        half8 a = *(const half8*)(ap + kt*32);
#pragma unroll
        for (int j = 0; j < 4; ++j) {
            half8 b = *(const half8*)(wl1p + ((kt*16 + w*4 + j) << 9) + (lane << 3));
            acc[j] = __builtin_amdgcn_mfma_f32_16x16x32_f16(a, b, acc[j], 0,0,0);
        }
    }
    float pr[4] = {0.f, 0.f, 0.f, 0.f};
#pragma unroll
    for (int j = 0; j < 4; ++j) {
        const int n = (w*4 + j)*16 + (lane & 15);
        const float blv = bl1[n], wmv = Wmu[n];
#pragma unroll
        for (int r = 0; r < 4; ++r)
            pr[r] += fmaxf(acc[j][r] + blv, 0.0f) * wmv;
    }
#pragma unroll
    for (int r = 0; r < 4; ++r)
#pragma unroll
        for (int o = 1; o < 16; o <<= 1) pr[r] += __shfl_xor(pr[r], o);
    if ((lane & 15) == 0) {
        const int g = lane >> 4;
#pragma unroll
        for (int r = 0; r < 4; ++r) hp[w][g*4 + r] = pr[r];
    }
    __syncthreads();
    if (tid < 16)
        out[(size_t)(b0 + tid)*Tn + ts] =
            hp[0][tid] + hp[1][tid] + hp[2][tid] + hp[3][tid] + bmu[0];
}

// pack weights: fp16 MFMA B-fragment order (B[k][n] = W[n][k]) for the
// f-net / wih / wl1; int8 B-fragment order (K=64) for Whh.
extern "C" __global__ void odernn_init(
    const float* __restrict__ W_ih, const float* __restrict__ W_hh,
    const float* __restrict__ W1,   const float* __restrict__ W2,
    const float* __restrict__ Wl1,
    _Float16* w1p, _Float16* w2p, signed char* whh8, _Float16* wih,
    _Float16* wl1p)
{
    const int idx = blockIdx.x * blockDim.x + threadIdx.x;
    const int stride = gridDim.x * blockDim.x;
    // W1: KT=16, NT=4 (N 50->64), K=512
    for (int p = idx; p < 32768; p += stride) {
        int j = p & 7, lane = (p >> 3) & 63, t = p >> 9;
        int nt = t & 3, kt = t >> 2;
        int n = nt*16 + (lane & 15), k = kt*32 + ((lane >> 4) << 3) + j;
        w1p[p] = (_Float16)((n < 50) ? W1[n*512 + k] : 0.f);
    }
    // W2: KT=2 (K 50->64), NT=32, N=512
    for (int p = idx; p < 32768; p += stride) {
        int j = p & 7, lane = (p >> 3) & 63, t = p >> 9;
        int nt = t & 31, kt = t >> 5;
        int n = nt*16 + (lane & 15), k = kt*32 + ((lane >> 4) << 3) + j;
        w2p[p] = (_Float16)((k < 50) ? W2[n*50 + k] : 0.f);
    }
    // Whh int8: KT=8 (K=64 each), NT=32; B frag: 16 bytes/lane,
    // n = nt*16+(lane&15), k = kt*64 + (lane>>4)*16 + j
    for (int p = idx; p < 262144; p += stride) {
        int j = p & 15, lane = (p >> 4) & 63, t = p >> 10;
        int nt = t & 31, kt = t >> 5;
        int n = nt*16 + (lane & 15), k = kt*64 + ((lane >> 4) << 4) + j;
        float v = rintf(W_hh[n*512 + k] * SB_WHH);
        v = fminf(127.0f, fmaxf(-127.0f, v));
        whh8[p] = (signed char)(int)v;
    }
    // Wih: KT=2, NT=32, K=64 (fp16)
    for (int p = idx; p < 32768; p += stride) {
        int j = p & 7, lane = (p >> 3) & 63, t = p >> 9;
        int nt = t & 31, kt = t >> 5;
        int n = nt*16 + (lane & 15), k = kt*32 + ((lane >> 4) << 3) + j;
        wih[p] = (_Float16)W_ih[n*64 + k];
    }
    // Wl1: KT=16, NT=16, N=256, K=512
    for (int p = idx; p < 131072; p += stride) {
        int j = p & 7, lane = (p >> 3) & 63, t = p >> 9;
        int nt = t & 15, kt = t >> 4;
        int n = nt*16 + (lane & 15), k = kt*32 + ((lane >> 4) << 3) + j;
        wl1p[p] = (_Float16)Wl1[n*512 + k];
    }
}

extern "C" void kernel_launch(void* const* d_in, const int* in_sizes, int n_in,
                              void* d_out, int out_size, void* d_ws, size_t ws_size,
                              hipStream_t stream)
{
    (void)in_sizes; (void)n_in; (void)out_size;
    const float* dt   = (const float*)d_in[0];
    const float* x    = (const float*)d_in[1];
    const float* W_ih = (const float*)d_in[2];
    const float* b_ih = (const float*)d_in[3];
    const float* W_hh = (const float*)d_in[4];
    const float* b_hh = (const float*)d_in[5];
    const float* W1   = (const float*)d_in[6];
    const float* b1   = (const float*)d_in[7];
    const float* W2   = (const float*)d_in[8];
    const float* b2   = (const float*)d_in[9];
    const float* Wl1  = (const float*)d_in[10];
    const float* bl1  = (const float*)d_in[11];
    const float* Wmu  = (const float*)d_in[12];
    const float* bmu  = (const float*)d_in[13];
    float* out = (float*)d_out;

    char* ws = (char*)d_ws;
    _Float16*    w1p  = (_Float16*)(ws);             // 64 KB
    _Float16*    w2p  = (_Float16*)(ws + 65536);     // 64 KB
    signed char* whh8 = (signed char*)(ws + 131072); // 256 KB (of 512 KB slot)
    _Float16*    wih  = (_Float16*)(ws + 655360);    // 64 KB
    _Float16*    wl1p = (_Float16*)(ws + 720896);    // 256 KB
    _Float16*    yg   = (_Float16*)(ws + 1048576);   // 105 MB (if available)

    const size_t need = 1048576 + (size_t)1024 * Tn * 512 * sizeof(_Float16);
    const int defer = (ws_size >= need) ? 1 : 0;

    odernn_init<<<256, 256, 0, stream>>>(W_ih, W_hh, W1, W2, Wl1,
                                         w1p, w2p, whh8, wih, wl1p);
    odernn_main<<<NWG, NTHR, 0, stream>>>(dt, x, b_ih, b_hh, b1, b2, bl1, Wmu, bmu,
                                          w1p, w2p, whh8, wih, wl1p,
                                          yg, out, defer);
    if (defer)
        odernn_head<<<(1024/16)*Tn, 256, 0, stream>>>(yg, wl1p, bl1, Wmu, bmu, out);
}

// Round 8
// 725.043 us; speedup vs baseline: 1.8075x; 1.4967x over previous
//
#include <hip/hip_runtime.h>
#include <math.h>

// ODE-RNN persistent kernel, round 19: ALL loop-invariant fragments in LDS.
// R18 post-mortem: bcx removed the accX spill (FETCH 3.06->1.93 GB, dur
// 1155->933us) but 74 B/thr/step of scratch re-reads remain = the w2f/w1f
// fragment arrays. Seven rounds prove this allocator will not keep hoisted
// half8 arrays in VGPRs across the 100-step loop under any attribute.
// R19: w1f/w2f -> LDS (w1L/w2L, 64+64 KB, wave-linear lane*16B layout --
// the storage tier that never spilled and never conflicted in R13/14/15).
// Register live-set across the loop is now just accQ(8)+k1(8)+scalars,
// comfortably inside the 64-VGPR granule. Keeps int8 Whh stream
// (576->320 KB/WG/step, absmax 0.00195 validated). LDS 148.5 KB, 1 WG/CU
// (all we ever achieved). Euler kept: 5 syncs/step.

#define NWG  256
#define NTHR 1024
#define Tn   100
#define Dn   64
#define Hn   512
#define Fn   50
#define YP   528   // fp16 pitch: 264 dwords == 8 mod 32 -> A-reads 2-way max
#define YQP  544   // i8 pitch: 136 dwords == 8 mod 32 -> uniform bank spread
#define XP   80
#define GPp  80
#define GPI  17
#define BXP  516   // bcx pitch (dwords): 16-lane consecutive access, no conflict
#define SB_WHH 2873.682f              // 127 / (1/sqrt(512))
#define QDH (1.0f/(125.0f*SB_WHH))    // dequant: (1/sA)*(1/sB)

typedef __attribute__((ext_vector_type(8))) _Float16 half8;
typedef __attribute__((ext_vector_type(4))) float f32x4;
typedef __attribute__((ext_vector_type(4))) int   i32x4;

__device__ __forceinline__ float my_tanh(float v) {
    float e = __expf(2.0f * v);
    return 1.0f - 2.0f / (e + 1.0f);   // exact 0 at v=0
}
__device__ __forceinline__ float wave_red(float v) {
#pragma unroll
    for (int o = 32; o > 0; o >>= 1) v += __shfl_down(v, o);
    return v;
}
__device__ __forceinline__ signed char q125(float v) {
    return (signed char)(int)rintf(v * 125.0f);
}

// f(y) = tanh(tanh(y@W1^T + b1)@W2^T + b2) * sc_row[r]. Two internal syncs.
// Wave w: GEMM1 job (kh=w>>2, nt1=w&3, 4 MFMA, B from w1L); GEMM2 n-tiles
// {w, w+16} (B from w2L). kout[i][r] valid in lanes<16.
__device__ __forceinline__ void feval(
    const _Float16* arg, const half8* w1b, const half8* w2b,
    float* gp, _Float16* gbf, const float b1v, const float b2v[2],
    const float* sc_row, int w, int lane, int tid, float kout[2][4])
{
    const int m4 = lane & 3, q = (lane >> 4) & 3;
    const int kh = w >> 2;
    f32x4 acc = {0.f, 0.f, 0.f, 0.f};
    const _Float16* arow = arg + m4 * YP + q * 8;
#pragma unroll
    for (int t = 0; t < 4; ++t) {
        half8 a = *(const half8*)(arow + (kh * 4 + t) * 32);
        acc = __builtin_amdgcn_mfma_f32_16x16x32_f16(a, w1b[t * 64], acc, 0, 0, 0);
    }
    if (lane < 16) {
#pragma unroll
        for (int r = 0; r < 4; ++r)
            gp[(w * 4 + r) * GPI + lane] = acc[r];
    }
    __syncthreads();
    if (tid < 256) {   // mid layer once: 4 rows x 64 neurons
        const int r = tid >> 6, n = tid & 63;
        const int nt = n >> 4, c = n & 15;
        float s = gp[((0*4 + nt) * 4 + r) * GPI + c]
                + gp[((1*4 + nt) * 4 + r) * GPI + c]
                + gp[((2*4 + nt) * 4 + r) * GPI + c]
                + gp[((3*4 + nt) * 4 + r) * GPI + c];
        float g = (n < Fn) ? my_tanh(s + b1v) : 0.0f;
        gbf[r * GPp + n] = (_Float16)g;
    }
    __syncthreads();
    half8 af0 = *(const half8*)(gbf + m4 * GPp + q * 8);
    half8 af1 = *(const half8*)(gbf + m4 * GPp + 32 + q * 8);
#pragma unroll
    for (int i = 0; i < 2; ++i) {
        f32x4 c = {0.f, 0.f, 0.f, 0.f};
        c = __builtin_amdgcn_mfma_f32_16x16x32_f16(af0, w2b[(i*2 + 0) * 64], c, 0, 0, 0);
        c = __builtin_amdgcn_mfma_f32_16x16x32_f16(af1, w2b[(i*2 + 1) * 64], c, 0, 0, 0);
        if (lane < 16) {
#pragma unroll
            for (int r = 0; r < 4; ++r)
                kout[i][r] = my_tanh(c[r] + b2v[i]) * sc_row[r];
        }
    }
}

extern "C" __global__ void __launch_bounds__(NTHR, 4)
odernn_main(const float* __restrict__ dt, const float* __restrict__ x,
            const float* __restrict__ b_ih, const float* __restrict__ b_hh,
            const float* __restrict__ b1,   const float* __restrict__ b2,
            const float* __restrict__ bl1,  const float* __restrict__ Wmu,
            const float* __restrict__ bmu,
            const _Float16* __restrict__ w1p,  const _Float16* __restrict__ w2p,
            const signed char* __restrict__ whh8, const _Float16* __restrict__ wih,
            const _Float16* __restrict__ wl1p,
            _Float16* __restrict__ yg, float* __restrict__ out, int defer)
{
    __shared__ __align__(16) _Float16 ybuf[4*YP];
    __shared__ __align__(16) signed char ybq[4*YQP];
    __shared__ __align__(16) _Float16 xbuf[4*XP];
    __shared__ __align__(16) _Float16 gbf[4*GPp];
    __shared__ __align__(16) float    gp[64*GPI];
    __shared__ __align__(16) float    bcx[4*BXP];
    __shared__ float sc_row[4], hp[64];
    // loop-invariant f-net B-fragments in LDS (the tier that never spills):
    // w1L: wave w slots 0..3; w2L: wave w slots [i][khalf]
    __shared__ __align__(16) _Float16 w1L[16 * 4 * 64 * 8];   // 64 KB
    __shared__ __align__(16) _Float16 w2L[16 * 4 * 64 * 8];   // 64 KB

    const int tid  = threadIdx.x;
    const int w    = tid >> 6;       // wave 0..15
    const int lane = tid & 63;
    const int m4   = lane & 3, q = (lane >> 4) & 3;
    const int cw   = lane & 15;
    const int row0 = blockIdx.x * 4;

    for (int i = tid; i < 4*YP;  i += NTHR) ybuf[i] = (_Float16)0.0f;
    for (int i = tid; i < 4*YQP; i += NTHR) ybq[i]  = 0;

    // stage loop-invariant fragments into LDS (once)
    {
        half8* w1d = ((half8*)w1L) + (w * 4) * 64 + lane;
        const int kh = w >> 2, nt1 = w & 3;
#pragma unroll
        for (int t = 0; t < 4; ++t) {
            const int kt = kh * 4 + t;
            w1d[t * 64] = ((const half8*)w1p)[(((kt << 2) + nt1) << 6) + lane];
        }
        half8* w2d = ((half8*)w2L) + (w * 4) * 64 + lane;
#pragma unroll
        for (int i = 0; i < 2; ++i) {
            const int nt = w + (i << 4);
            w2d[(i*2 + 0) * 64] = ((const half8*)w2p)[(nt << 6) + lane];
            w2d[(i*2 + 1) * 64] = ((const half8*)w2p)[((32 + nt) << 6) + lane];
        }
    }

    float bC[2], b2v[2];
    int ci[2];
#pragma unroll
    for (int i = 0; i < 2; ++i) {
        const int n = (w + i*16)*16 + cw;
        bC[i]  = b_ih[n] + b_hh[n];
        b2v[i] = b2[n];
        ci[i]  = n;
    }
    const float b1v = (tid < 256 && (tid & 63) < Fn) ? b1[tid & 63] : 0.0f;
    const float blv = bl1[w*16 + cw];   // fallback head only
    const float wmv = Wmu[w*16 + cw];
    const float bmu0 = bmu[0];

    const half8* w1b = ((const half8*)w1L) + (w * 4) * 64 + lane;
    const half8* w2b = ((const half8*)w2L) + (w * 4) * 64 + lane;

    float k1[2][4];
    float xv = 0.f, scn = 0.f;

    // stage x/sc for ts = 0
    if (tid < 256) {
        const int r = tid >> 6, c = tid & 63;
        xbuf[r*XP + c] = (_Float16)x[((size_t)(row0 + r)*Tn + 0)*Dn + c];
    }
    if (tid < 4) {
        const size_t di = ((size_t)(row0 + tid)*Tn + 0)*2;
        sc_row[tid] = (dt[di + 1] - dt[di]) * 0.01f;
    }
    __syncthreads();

#pragma unroll 1
    for (int ts = 0; ts < Tn; ++ts) {
        // ---- Phase A: x@Wih (fp16 MFMA) + bias -> LDS bcx; accX dies here ----
        {
            f32x4 accX0 = {0.f,0.f,0.f,0.f};
            f32x4 accX1 = {0.f,0.f,0.f,0.f};
            const _Float16* xh = xbuf + m4*XP + q*8;
#pragma unroll
            for (int kt = 0; kt < 2; ++kt) {
                half8 ah = *(const half8*)(xh + kt*32);
                half8 bw0 = *(const half8*)(wih + (((kt*32 + w)      << 9) + (lane << 3)));
                half8 bw1 = *(const half8*)(wih + (((kt*32 + w + 16) << 9) + (lane << 3)));
                accX0 = __builtin_amdgcn_mfma_f32_16x16x32_f16(ah, bw0, accX0, 0,0,0);
                accX1 = __builtin_amdgcn_mfma_f32_16x16x32_f16(ah, bw1, accX1, 0,0,0);
            }
            if (lane < 16) {
#pragma unroll
                for (int r = 0; r < 4; ++r) {
                    bcx[r*BXP + ci[0]] = accX0[r] + bC[0];
                    bcx[r*BXP + ci[1]] = accX1[r] + bC[1];
                }
            }
        }
        __builtin_amdgcn_sched_barrier(0);   // pin phase: accX must die here

        // ---- Phase B: h@Whh int8 MFMA (K=64, 8 kt x 2 n-tiles, 256 KB/step) ----
        i32x4 accQ0 = {0,0,0,0};
        i32x4 accQ1 = {0,0,0,0};
        {
            const signed char* yq = ybq + m4*YQP + q*16;
#pragma unroll
            for (int kt = 0; kt < 8; ++kt) {
                i32x4 a = *(const i32x4*)(yq + kt*64);
                i32x4 b0 = *(const i32x4*)(whh8 + (((kt*32 + w)      << 10) + (lane << 4)));
                i32x4 b1h= *(const i32x4*)(whh8 + (((kt*32 + w + 16) << 10) + (lane << 4)));
                accQ0 = __builtin_amdgcn_mfma_i32_16x16x64_i8(a, b0,  accQ0, 0,0,0);
                accQ1 = __builtin_amdgcn_mfma_i32_16x16x64_i8(a, b1h, accQ1, 0,0,0);
            }
        }
        __syncthreads();   // S1: all A-reads of old ybq/xbuf done; bcx visible
        if (lane < 16) {
#pragma unroll
            for (int r = 0; r < 4; ++r) {
                float y0a = my_tanh((float)accQ0[r] * QDH + bcx[r*BXP + ci[0]]);
                ybuf[r*YP + ci[0]] = (_Float16)y0a;
                ybq[r*YQP + ci[0]] = q125(y0a);
                float y0b = my_tanh((float)accQ1[r] * QDH + bcx[r*BXP + ci[1]]);
                ybuf[r*YP + ci[1]] = (_Float16)y0b;
                ybq[r*YQP + ci[1]] = q125(y0b);
            }
        }
        // prefetch x/dt for next step (lands during feval)
        {
            const int tsn = (ts + 1 < Tn) ? ts + 1 : ts;
            if (tid < 256) {
                const int r = tid >> 6, c = tid & 63;
                xv = x[((size_t)(row0 + r)*Tn + tsn)*Dn + c];
            }
            if (tid < 4) {
                const size_t di = ((size_t)(row0 + tid)*Tn + tsn)*2;
                scn = (dt[di + 1] - dt[di]) * 0.01f;
            }
        }
        __syncthreads();   // S2: y0 visible

        // ---- ODE: Euler step, h = 1 (feval has 2 syncs: S3, S4) ----
        feval(ybuf, w1b, w2b, gp, gbf, b1v, b2v, sc_row, w, lane, tid, k1);

        // y_new = y0 (re-read fp16) + k1; stage next x/sc
        if (lane < 16) {
#pragma unroll
            for (int i = 0; i < 2; ++i)
#pragma unroll
                for (int r = 0; r < 4; ++r) {
                    float yn = (float)ybuf[r*YP + ci[i]] + k1[i][r];
                    ybuf[r*YP + ci[i]] = (_Float16)yn;
                    ybq[r*YQP + ci[i]] = q125(yn);
                }
        }
        if (tid < 256) xbuf[(tid >> 6)*XP + (tid & 63)] = (_Float16)xv;
        if (tid < 4)   sc_row[tid] = scn;
        __syncthreads();   // S5: ynew + x + sc visible

        if (defer) {
            // store y (fp16) for phase-2 head; coalesced dword per thread
            const int r = tid >> 8, c = (tid & 255) * 2;
            unsigned u = *(const unsigned*)(ybuf + r*YP + c);
            *(unsigned*)(yg + (((size_t)(row0 + r)*Tn + ts)*512 + c)) = u;
        } else {
            // in-loop head (fallback)
            f32x4 aH = {0.f,0.f,0.f,0.f};
            const _Float16* yh = ybuf + m4*YP + q*8;
#pragma unroll 4
            for (int kt = 0; kt < 16; ++kt) {
                half8 ah = *(const half8*)(yh + kt*32);
                half8 b = *(const half8*)(wl1p + ((kt*16 + w) << 9) + (lane << 3));
                aH = __builtin_amdgcn_mfma_f32_16x16x32_f16(ah, b, aH, 0,0,0);
            }
            float pr[4];
#pragma unroll
            for (int r = 0; r < 4; ++r) {
                float p = (lane < 16) ? fmaxf(aH[r] + blv, 0.0f) * wmv : 0.0f;
                pr[r] = wave_red(p);
            }
            if (lane == 0) {
#pragma unroll
                for (int r = 0; r < 4; ++r) hp[w*4 + r] = pr[r];
            }
            __syncthreads();
            if (tid < 4) {
                float s = bmu0;
#pragma unroll
                for (int wv = 0; wv < 16; ++wv) s += hp[wv*4 + tid];
                out[(size_t)(row0 + tid)*Tn + ts] = s;
            }
            __syncthreads();
        }
    }
}

// phase-2 head: out[b,t] = relu(y[b,t]@Wl1^T + bl1)@Wmu^T + bmu
// grid = (B/16)*Tn WGs x 256 threads; wave w covers n in [w*64,(w+1)*64)
extern "C" __global__ void __launch_bounds__(256, 4)
odernn_head(const _Float16* __restrict__ yg, const _Float16* __restrict__ wl1p,
            const float* __restrict__ bl1, const float* __restrict__ Wmu,
            const float* __restrict__ bmu, float* __restrict__ out)
{
    __shared__ float hp[4][16];
    const int tid = threadIdx.x, w = tid >> 6, lane = tid & 63;
    const int q = (lane >> 4) & 3;
    const int b0 = (blockIdx.x / Tn) * 16, ts = blockIdx.x % Tn;

    f32x4 acc[4];
#pragma unroll
    for (int j = 0; j < 4; ++j) acc[j] = (f32x4){0.f,0.f,0.f,0.f};
    const _Float16* ap = yg + ((size_t)(b0 + (lane & 15))*Tn + ts)*512 + q*8;
#pragma unroll 4
    for (int kt = 0; kt < 16; ++kt) {
        half8 a = *(const half8*)(ap + kt*32);
#pragma unroll
        for (int j = 0; j < 4; ++j) {
            half8 b = *(const half8*)(wl1p + ((kt*16 + w*4 + j) << 9) + (lane << 3));
            acc[j] = __builtin_amdgcn_mfma_f32_16x16x32_f16(a, b, acc[j], 0,0,0);
        }
    }
    float pr[4] = {0.f, 0.f, 0.f, 0.f};
#pragma unroll
    for (int j = 0; j < 4; ++j) {
        const int n = (w*4 + j)*16 + (lane & 15);
        const float blv = bl1[n], wmv = Wmu[n];
#pragma unroll
        for (int r = 0; r < 4; ++r)
            pr[r] += fmaxf(acc[j][r] + blv, 0.0f) * wmv;
    }
#pragma unroll
    for (int r = 0; r < 4; ++r)
#pragma unroll
        for (int o = 1; o < 16; o <<= 1) pr[r] += __shfl_xor(pr[r], o);
    if ((lane & 15) == 0) {
        const int g = lane >> 4;
#pragma unroll
        for (int r = 0; r < 4; ++r) hp[w][g*4 + r] = pr[r];
    }
    __syncthreads();
    if (tid < 16)
        out[(size_t)(b0 + tid)*Tn + ts] =
            hp[0][tid] + hp[1][tid] + hp[2][tid] + hp[3][tid] + bmu[0];
}

// pack weights: fp16 MFMA B-fragment order (B[k][n] = W[n][k]) for the
// f-net / wih / wl1; int8 B-fragment order (K=64) for Whh.
extern "C" __global__ void odernn_init(
    const float* __restrict__ W_ih, const float* __restrict__ W_hh,
    const float* __restrict__ W1,   const float* __restrict__ W2,
    const float* __restrict__ Wl1,
    _Float16* w1p, _Float16* w2p, signed char* whh8, _Float16* wih,
    _Float16* wl1p)
{
    const int idx = blockIdx.x * blockDim.x + threadIdx.x;
    const int stride = gridDim.x * blockDim.x;
    // W1: KT=16, NT=4 (N 50->64), K=512
    for (int p = idx; p < 32768; p += stride) {
        int j = p & 7, lane = (p >> 3) & 63, t = p >> 9;
        int nt = t & 3, kt = t >> 2;
        int n = nt*16 + (lane & 15), k = kt*32 + ((lane >> 4) << 3) + j;
        w1p[p] = (_Float16)((n < 50) ? W1[n*512 + k] : 0.f);
    }
    // W2: KT=2 (K 50->64), NT=32, N=512
    for (int p = idx; p < 32768; p += stride) {
        int j = p & 7, lane = (p >> 3) & 63, t = p >> 9;
        int nt = t & 31, kt = t >> 5;
        int n = nt*16 + (lane & 15), k = kt*32 + ((lane >> 4) << 3) + j;
        w2p[p] = (_Float16)((k < 50) ? W2[n*50 + k] : 0.f);
    }
    // Whh int8: KT=8 (K=64 each), NT=32; B frag: 16 bytes/lane,
    // n = nt*16+(lane&15), k = kt*64 + (lane>>4)*16 + j
    for (int p = idx; p < 262144; p += stride) {
        int j = p & 15, lane = (p >> 4) & 63, t = p >> 10;
        int nt = t & 31, kt = t >> 5;
        int n = nt*16 + (lane & 15), k = kt*64 + ((lane >> 4) << 4) + j;
        float v = rintf(W_hh[n*512 + k] * SB_WHH);
        v = fminf(127.0f, fmaxf(-127.0f, v));
        whh8[p] = (signed char)(int)v;
    }
    // Wih: KT=2, NT=32, K=64 (fp16)
    for (int p = idx; p < 32768; p += stride) {
        int j = p & 7, lane = (p >> 3) & 63, t = p >> 9;
        int nt = t & 31, kt = t >> 5;
        int n = nt*16 + (lane & 15), k = kt*32 + ((lane >> 4) << 3) + j;
        wih[p] = (_Float16)W_ih[n*64 + k];
    }
    // Wl1: KT=16, NT=16, N=256, K=512
    for (int p = idx; p < 131072; p += stride) {
        int j = p & 7, lane = (p >> 3) & 63, t = p >> 9;
        int nt = t & 15, kt = t >> 4;
        int n = nt*16 + (lane & 15), k = kt*32 + ((lane >> 4) << 3) + j;
        wl1p[p] = (_Float16)Wl1[n*512 + k];
    }
}

extern "C" void kernel_launch(void* const* d_in, const int* in_sizes, int n_in,
                              void* d_out, int out_size, void* d_ws, size_t ws_size,
                              hipStream_t stream)
{
    (void)in_sizes; (void)n_in; (void)out_size;
    const float* dt   = (const float*)d_in[0];
    const float* x    = (const float*)d_in[1];
    const float* W_ih = (const float*)d_in[2];
    const float* b_ih = (const float*)d_in[3];
    const float* W_hh = (const float*)d_in[4];
    const float* b_hh = (const float*)d_in[5];
    const float* W1   = (const float*)d_in[6];
    const float* b1   = (const float*)d_in[7];
    const float* W2   = (const float*)d_in[8];
    const float* b2   = (const float*)d_in[9];
    const float* Wl1  = (const float*)d_in[10];
    const float* bl1  = (const float*)d_in[11];
    const float* Wmu  = (const float*)d_in[12];
    const float* bmu  = (const float*)d_in[13];
    float* out = (float*)d_out;

    char* ws = (char*)d_ws;
    _Float16*    w1p  = (_Float16*)(ws);             // 64 KB
    _Float16*    w2p  = (_Float16*)(ws + 65536);     // 64 KB
    signed char* whh8 = (signed char*)(ws + 131072); // 256 KB (of 512 KB slot)
    _Float16*    wih  = (_Float16*)(ws + 655360);    // 64 KB
    _Float16*    wl1p = (_Float16*)(ws + 720896);    // 256 KB
    _Float16*    yg   = (_Float16*)(ws + 1048576);   // 105 MB (if available)

    const size_t need = 1048576 + (size_t)1024 * Tn * 512 * sizeof(_Float16);
    const int defer = (ws_size >= need) ? 1 : 0;

    odernn_init<<<256, 256, 0, stream>>>(W_ih, W_hh, W1, W2, Wl1,
                                         w1p, w2p, whh8, wih, wl1p);
    odernn_main<<<NWG, NTHR, 0, stream>>>(dt, x, b_ih, b_hh, b1, b2, bl1, Wmu, bmu,
                                          w1p, w2p, whh8, wih, wl1p,
                                          yg, out, defer);
    if (defer)
        odernn_head<<<(1024/16)*Tn, 256, 0, stream>>>(yg, wl1p, bl1, Wmu, bmu, out);
}

// Round 11
// 724.093 us; speedup vs baseline: 1.8098x; 1.0013x over previous
//
#include <hip/hip_runtime.h>
#include <math.h>

// ODE-RNN persistent kernel, round 22: AGPR-resident Whh, ATOMIC load block.
// R20/R21 post-mortem: corruption (absmax 0.11/0.15) was NOT MFMA hazards --
// it was separate per-load "=a" asm statements + a detached s_waitcnt: the
// allocator sees bq* as defined at each load-asm and may insert register
// shuffling COPIES before the load lands -> garbage fragments. R22 puts all
// 16 global_load_dwordx4 + s_waitcnt vmcnt(0) in ONE asm volatile block:
// at the block boundary every output is complete; later copies are safe.
// Trailing MFMA-D->VALU s_nops moved INSIDE the last QMM asm (R21's
// free-floating nops weren't data-ordered vs the dequant reads).
// Body otherwise = R19 (582us, FETCH 20MB, absmax 0.00208). Whh stream
// 256KB/WG/step -> 0; only wih (64KB) streams. Declared rule: absmax>5e-3
// => AGPR line dead, revert to R19 next round.

#define NWG  256
#define NTHR 1024
#define Tn   100
#define Dn   64
#define Hn   512
#define Fn   50
#define YP   528   // fp16 pitch: 264 dwords == 8 mod 32 -> A-reads 2-way max
#define YQP  544   // i8 pitch: 136 dwords == 8 mod 32 -> uniform bank spread
#define XP   80
#define GPp  80
#define GPI  17
#define BXP  516   // bcx pitch (dwords): 16-lane consecutive access, no conflict
#define SB_WHH 2873.682f              // 127 / (1/sqrt(512))
#define QDH (1.0f/(125.0f*SB_WHH))    // dequant: (1/sA)*(1/sB)

typedef __attribute__((ext_vector_type(8))) _Float16 half8;
typedef __attribute__((ext_vector_type(4))) float f32x4;
typedef __attribute__((ext_vector_type(4))) int   i32x4;

__device__ __forceinline__ float my_tanh(float v) {
    float e = __expf(2.0f * v);
    return 1.0f - 2.0f / (e + 1.0f);   // exact 0 at v=0
}
__device__ __forceinline__ float wave_red(float v) {
#pragma unroll
    for (int o = 32; o > 0; o >>= 1) v += __shfl_down(v, o);
    return v;
}
__device__ __forceinline__ signed char q125(float v) {
    return (signed char)(int)rintf(v * 125.0f);
}

// f(y) = tanh(tanh(y@W1^T + b1)@W2^T + b2) * sc_row[r]. Two internal syncs.
// Wave w: GEMM1 job (kh=w>>2, nt1=w&3, 4 MFMA, B from w1L); GEMM2 n-tiles
// {w, w+16} (B from w2L). kout[i][r] valid in lanes<16.
__device__ __forceinline__ void feval(
    const _Float16* arg, const half8* w1b, const half8* w2b,
    float* gp, _Float16* gbf, const float b1v, const float b2v[2],
    const float* sc_row, int w, int lane, int tid, float kout[2][4])
{
    const int m4 = lane & 3, q = (lane >> 4) & 3;
    const int kh = w >> 2;
    f32x4 acc = {0.f, 0.f, 0.f, 0.f};
    const _Float16* arow = arg + m4 * YP + q * 8;
#pragma unroll
    for (int t = 0; t < 4; ++t) {
        half8 a = *(const half8*)(arow + (kh * 4 + t) * 32);
        acc = __builtin_amdgcn_mfma_f32_16x16x32_f16(a, w1b[t * 64], acc, 0, 0, 0);
    }
    if (lane < 16) {
#pragma unroll
        for (int r = 0; r < 4; ++r)
            gp[(w * 4 + r) * GPI + lane] = acc[r];
    }
    __syncthreads();
    if (tid < 256) {   // mid layer once: 4 rows x 64 neurons
        const int r = tid >> 6, n = tid & 63;
        const int nt = n >> 4, c = n & 15;
        float s = gp[((0*4 + nt) * 4 + r) * GPI + c]
                + gp[((1*4 + nt) * 4 + r) * GPI + c]
                + gp[((2*4 + nt) * 4 + r) * GPI + c]
                + gp[((3*4 + nt) * 4 + r) * GPI + c];
        float g = (n < Fn) ? my_tanh(s + b1v) : 0.0f;
        gbf[r * GPp + n] = (_Float16)g;
    }
    __syncthreads();
    half8 af0 = *(const half8*)(gbf + m4 * GPp + q * 8);
    half8 af1 = *(const half8*)(gbf + m4 * GPp + 32 + q * 8);
#pragma unroll
    for (int i = 0; i < 2; ++i) {
        f32x4 c = {0.f, 0.f, 0.f, 0.f};
        c = __builtin_amdgcn_mfma_f32_16x16x32_f16(af0, w2b[(i*2 + 0) * 64], c, 0, 0, 0);
        c = __builtin_amdgcn_mfma_f32_16x16x32_f16(af1, w2b[(i*2 + 1) * 64], c, 0, 0, 0);
        if (lane < 16) {
#pragma unroll
            for (int r = 0; r < 4; ++r)
                kout[i][r] = my_tanh(c[r] + b2v[i]) * sc_row[r];
        }
    }
}

extern "C" __global__ void __launch_bounds__(NTHR, 4)
odernn_main(const float* __restrict__ dt, const float* __restrict__ x,
            const float* __restrict__ b_ih, const float* __restrict__ b_hh,
            const float* __restrict__ b1,   const float* __restrict__ b2,
            const float* __restrict__ bl1,  const float* __restrict__ Wmu,
            const float* __restrict__ bmu,
            const _Float16* __restrict__ w1p,  const _Float16* __restrict__ w2p,
            const signed char* __restrict__ whh8, const _Float16* __restrict__ wih,
            const _Float16* __restrict__ wl1p,
            _Float16* __restrict__ yg, float* __restrict__ out, int defer)
{
    __shared__ __align__(16) _Float16 ybuf[4*YP];
    __shared__ __align__(16) signed char ybq[4*YQP];
    __shared__ __align__(16) _Float16 xbuf[4*XP];
    __shared__ __align__(16) _Float16 gbf[4*GPp];
    __shared__ __align__(16) float    gp[64*GPI];
    __shared__ __align__(16) float    bcx[4*BXP];
    __shared__ float sc_row[4], hp[64];
    __shared__ __align__(16) _Float16 w1L[16 * 4 * 64 * 8];   // 64 KB
    __shared__ __align__(16) _Float16 w2L[16 * 4 * 64 * 8];   // 64 KB

    const int tid  = threadIdx.x;
    const int w    = tid >> 6;       // wave 0..15
    const int lane = tid & 63;
    const int m4   = lane & 3, q = (lane >> 4) & 3;
    const int cw   = lane & 15;
    const int row0 = blockIdx.x * 4;

    for (int i = tid; i < 4*YP;  i += NTHR) ybuf[i] = (_Float16)0.0f;
    for (int i = tid; i < 4*YQP; i += NTHR) ybq[i]  = 0;

    // stage loop-invariant f-net fragments into LDS (once; R19-proven)
    {
        half8* w1d = ((half8*)w1L) + (w * 4) * 64 + lane;
        const int kh = w >> 2, nt1 = w & 3;
#pragma unroll
        for (int t = 0; t < 4; ++t) {
            const int kt = kh * 4 + t;
            w1d[t * 64] = ((const half8*)w1p)[(((kt << 2) + nt1) << 6) + lane];
        }
        half8* w2d = ((half8*)w2L) + (w * 4) * 64 + lane;
#pragma unroll
        for (int i = 0; i < 2; ++i) {
            const int nt = w + (i << 4);
            w2d[(i*2 + 0) * 64] = ((const half8*)w2p)[(nt << 6) + lane];
            w2d[(i*2 + 1) * 64] = ((const half8*)w2p)[((32 + nt) << 6) + lane];
        }
    }

    // ---- Whh int8 B-fragments -> AGPRs in ONE atomic asm block (64 AGPRs).
    // All 16 loads + s_waitcnt vmcnt(0) in a single volatile asm: outputs
    // are architecturally complete at the block boundary, so any allocator
    // copies afterwards move REAL data (the R20/R21 corruption was copies
    // inserted between detached load-asm statements and a detached waitcnt).
    i32x4 bq0,  bq1,  bq2,  bq3,  bq4,  bq5,  bq6,  bq7;
    i32x4 bq8,  bq9,  bq10, bq11, bq12, bq13, bq14, bq15;
#define WADDR(kt, ntadd) (whh8 + ((((kt)*32 + w + (ntadd)) << 10) + (lane << 4)))
    asm volatile(
        "global_load_dwordx4 %0, %16, off\n\t"
        "global_load_dwordx4 %1, %17, off\n\t"
        "global_load_dwordx4 %2, %18, off\n\t"
        "global_load_dwordx4 %3, %19, off\n\t"
        "global_load_dwordx4 %4, %20, off\n\t"
        "global_load_dwordx4 %5, %21, off\n\t"
        "global_load_dwordx4 %6, %22, off\n\t"
        "global_load_dwordx4 %7, %23, off\n\t"
        "global_load_dwordx4 %8, %24, off\n\t"
        "global_load_dwordx4 %9, %25, off\n\t"
        "global_load_dwordx4 %10, %26, off\n\t"
        "global_load_dwordx4 %11, %27, off\n\t"
        "global_load_dwordx4 %12, %28, off\n\t"
        "global_load_dwordx4 %13, %29, off\n\t"
        "global_load_dwordx4 %14, %30, off\n\t"
        "global_load_dwordx4 %15, %31, off\n\t"
        "s_waitcnt vmcnt(0)"
        : "=a"(bq0),  "=a"(bq1),  "=a"(bq2),  "=a"(bq3),
          "=a"(bq4),  "=a"(bq5),  "=a"(bq6),  "=a"(bq7),
          "=a"(bq8),  "=a"(bq9),  "=a"(bq10), "=a"(bq11),
          "=a"(bq12), "=a"(bq13), "=a"(bq14), "=a"(bq15)
        : "v"(WADDR(0,0)),  "v"(WADDR(0,16)),
          "v"(WADDR(1,0)),  "v"(WADDR(1,16)),
          "v"(WADDR(2,0)),  "v"(WADDR(2,16)),
          "v"(WADDR(3,0)),  "v"(WADDR(3,16)),
          "v"(WADDR(4,0)),  "v"(WADDR(4,16)),
          "v"(WADDR(5,0)),  "v"(WADDR(5,16)),
          "v"(WADDR(6,0)),  "v"(WADDR(6,16)),
          "v"(WADDR(7,0)),  "v"(WADDR(7,16))
        : "memory");
#undef WADDR

    float bC[2], b2v[2];
    int ci[2];
#pragma unroll
    for (int i = 0; i < 2; ++i) {
        const int n = (w + i*16)*16 + cw;
        bC[i]  = b_ih[n] + b_hh[n];
        b2v[i] = b2[n];
        ci[i]  = n;
    }
    const float b1v = (tid < 256 && (tid & 63) < Fn) ? b1[tid & 63] : 0.0f;
    const float blv = bl1[w*16 + cw];   // fallback head only
    const float wmv = Wmu[w*16 + cw];
    const float bmu0 = bmu[0];

    const half8* w1b = ((const half8*)w1L) + (w * 4) * 64 + lane;
    const half8* w2b = ((const half8*)w2L) + (w * 4) * 64 + lane;

    float k1[2][4];
    float xv = 0.f, scn = 0.f;

    // stage x/sc for ts = 0
    if (tid < 256) {
        const int r = tid >> 6, c = tid & 63;
        xbuf[r*XP + c] = (_Float16)x[((size_t)(row0 + r)*Tn + 0)*Dn + c];
    }
    if (tid < 4) {
        const size_t di = ((size_t)(row0 + tid)*Tn + 0)*2;
        sc_row[tid] = (dt[di + 1] - dt[di]) * 0.01f;
    }
    __syncthreads();

#pragma unroll 1
    for (int ts = 0; ts < Tn; ++ts) {
        // ---- Phase A: x@Wih (fp16 MFMA) + bias -> LDS bcx; accX dies here ----
        {
            f32x4 accX0 = {0.f,0.f,0.f,0.f};
            f32x4 accX1 = {0.f,0.f,0.f,0.f};
            const _Float16* xh = xbuf + m4*XP + q*8;
#pragma unroll
            for (int kt = 0; kt < 2; ++kt) {
                half8 ah = *(const half8*)(xh + kt*32);
                half8 bw0 = *(const half8*)(wih + (((kt*32 + w)      << 9) + (lane << 3)));
                half8 bw1 = *(const half8*)(wih + (((kt*32 + w + 16) << 9) + (lane << 3)));
                accX0 = __builtin_amdgcn_mfma_f32_16x16x32_f16(ah, bw0, accX0, 0,0,0);
                accX1 = __builtin_amdgcn_mfma_f32_16x16x32_f16(ah, bw1, accX1, 0,0,0);
            }
            if (lane < 16) {
#pragma unroll
                for (int r = 0; r < 4; ++r) {
                    bcx[r*BXP + ci[0]] = accX0[r] + bC[0];
                    bcx[r*BXP + ci[1]] = accX1[r] + bC[1];
                }
            }
        }
        __builtin_amdgcn_sched_barrier(0);   // pin phase: accX must die here

        // ---- Phase B: h@Whh int8 MFMA, B from AGPRs (no stream).
        // s_nop 3 in first block: VALU zero-init -> MFMA SrcC wait-states.
        // s_nop 7 x3 INSIDE last block: MFMA D -> VALU read (ordered).
        i32x4 accQ0 = {0,0,0,0};
        i32x4 accQ1 = {0,0,0,0};
        {
            const signed char* yq = ybq + m4*YQP + q*16;
            i32x4 aq;
#define QMM(kt, B0, B1, PRE, POST) { \
            aq = *(const i32x4*)(yq + (kt)*64); \
            asm(PRE \
                "v_mfma_i32_16x16x64_i8 %0, %2, %3, %0\n\t" \
                "v_mfma_i32_16x16x64_i8 %1, %2, %4, %1" \
                POST \
                : "+v"(accQ0), "+v"(accQ1) \
                : "v"(aq), "a"(B0), "a"(B1)); }
            QMM(0, bq0,  bq1,  "s_nop 3\n\t", "")
            QMM(1, bq2,  bq3,  "", "")
            QMM(2, bq4,  bq5,  "", "")
            QMM(3, bq6,  bq7,  "", "")
            QMM(4, bq8,  bq9,  "", "")
            QMM(5, bq10, bq11, "", "")
            QMM(6, bq12, bq13, "", "")
            QMM(7, bq14, bq15, "", "\n\ts_nop 7\n\ts_nop 7\n\ts_nop 7")
#undef QMM
        }
        __syncthreads();   // S1: all A-reads of old ybq/xbuf done; bcx visible
        if (lane < 16) {
#pragma unroll
            for (int r = 0; r < 4; ++r) {
                float y0a = my_tanh((float)accQ0[r] * QDH + bcx[r*BXP + ci[0]]);
                ybuf[r*YP + ci[0]] = (_Float16)y0a;
                ybq[r*YQP + ci[0]] = q125(y0a);
                float y0b = my_tanh((float)accQ1[r] * QDH + bcx[r*BXP + ci[1]]);
                ybuf[r*YP + ci[1]] = (_Float16)y0b;
                ybq[r*YQP + ci[1]] = q125(y0b);
            }
        }
        // prefetch x/dt for next step (lands during feval)
        {
            const int tsn = (ts + 1 < Tn) ? ts + 1 : ts;
            if (tid < 256) {
                const int r = tid >> 6, c = tid & 63;
                xv = x[((size_t)(row0 + r)*Tn + tsn)*Dn + c];
            }
            if (tid < 4) {
                const size_t di = ((size_t)(row0 + tid)*Tn + tsn)*2;
                scn = (dt[di + 1] - dt[di]) * 0.01f;
            }
        }
        __syncthreads();   // S2: y0 visible

        // ---- ODE: Euler step, h = 1 (feval has 2 syncs: S3, S4) ----
        feval(ybuf, w1b, w2b, gp, gbf, b1v, b2v, sc_row, w, lane, tid, k1);

        // y_new = y0 (re-read fp16) + k1; stage next x/sc
        if (lane < 16) {
#pragma unroll
            for (int i = 0; i < 2; ++i)
#pragma unroll
                for (int r = 0; r < 4; ++r) {
                    float yn = (float)ybuf[r*YP + ci[i]] + k1[i][r];
                    ybuf[r*YP + ci[i]] = (_Float16)yn;
                    ybq[r*YQP + ci[i]] = q125(yn);
                }
        }
        if (tid < 256) xbuf[(tid >> 6)*XP + (tid & 63)] = (_Float16)xv;
        if (tid < 4)   sc_row[tid] = scn;
        __syncthreads();   // S5: ynew + x + sc visible

        if (defer) {
            // store y (fp16) for phase-2 head; coalesced dword per thread
            const int r = tid >> 8, c = (tid & 255) * 2;
            unsigned u = *(const unsigned*)(ybuf + r*YP + c);
            *(unsigned*)(yg + (((size_t)(row0 + r)*Tn + ts)*512 + c)) = u;
        } else {
            // in-loop head (fallback)
            f32x4 aH = {0.f,0.f,0.f,0.f};
            const _Float16* yh = ybuf + m4*YP + q*8;
#pragma unroll 4
            for (int kt = 0; kt < 16; ++kt) {
                half8 ah = *(const half8*)(yh + kt*32);
                half8 b = *(const half8*)(wl1p + ((kt*16 + w) << 9) + (lane << 3));
                aH = __builtin_amdgcn_mfma_f32_16x16x32_f16(ah, b, aH, 0,0,0);
            }
            float pr[4];
#pragma unroll
            for (int r = 0; r < 4; ++r) {
                float p = (lane < 16) ? fmaxf(aH[r] + blv, 0.0f) * wmv : 0.0f;
                pr[r] = wave_red(p);
            }
            if (lane == 0) {
#pragma unroll
                for (int r = 0; r < 4; ++r) hp[w*4 + r] = pr[r];
            }
            __syncthreads();
            if (tid < 4) {
                float s = bmu0;
#pragma unroll
                for (int wv = 0; wv < 16; ++wv) s += hp[wv*4 + tid];
                out[(size_t)(row0 + tid)*Tn + ts] = s;
            }
            __syncthreads();
        }
    }
}

// phase-2 head: out[b,t] = relu(y[b,t]@Wl1^T + bl1)@Wmu^T + bmu
// grid = (B/16)*Tn WGs x 256 threads; wave w covers n in [w*64,(w+1)*64)
extern "C" __global__ void __launch_bounds__(256, 4)
odernn_head(const _Float16* __restrict__ yg, const _Float16* __restrict__ wl1p,
            const float* __restrict__ bl1, const float* __restrict__ Wmu,
            const float* __restrict__ bmu, float* __restrict__ out)
{
    __shared__ float hp[4][16];
    const int tid = threadIdx.x, w = tid >> 6, lane = tid & 63;
    const int q = (lane >> 4) & 3;
    const int b0 = (blockIdx.x / Tn) * 16, ts = blockIdx.x % Tn;

    f32x4 acc[4];
#pragma unroll
    for (int j = 0; j < 4; ++j) acc[j] = (f32x4){0.f,0.f,0.f,0.f};
    const _Float16* ap = yg + ((size_t)(b0 + (lane & 15))*Tn + ts)*512 + q*8;
#pragma unroll 4
    for (int kt = 0; kt < 16; ++kt) {
        half8 a = *(const half8*)(ap + kt*32);
#pragma unroll
        for (int j = 0; j < 4; ++j) {
            half8 b = *(const half8*)(wl1p + ((kt*16 + w*4 + j) << 9) + (lane << 3));
            acc[j] = __builtin_amdgcn_mfma_f32_16x16x32_f16(a, b, acc[j], 0,0,0);
        }
    }
    float pr[4] = {0.f, 0.f, 0.f, 0.f};
#pragma unroll
    for (int j = 0; j < 4; ++j) {
        const int n = (w*4 + j)*16 + (lane & 15);
        const float blv = bl1[n], wmv = Wmu[n];
#pragma unroll
        for (int r = 0; r < 4; ++r)
            pr[r] += fmaxf(acc[j][r] + blv, 0.0f) * wmv;
    }
#pragma unroll
    for (int r = 0; r < 4; ++r)
#pragma unroll
        for (int o = 1; o < 16; o <<= 1) pr[r] += __shfl_xor(pr[r], o);
    if ((lane & 15) == 0) {
        const int g = lane >> 4;
#pragma unroll
        for (int r = 0; r < 4; ++r) hp[w][g*4 + r] = pr[r];
    }
    __syncthreads();
    if (tid < 16)
        out[(size_t)(b0 + tid)*Tn + ts] =
            hp[0][tid] + hp[1][tid] + hp[2][tid] + hp[3][tid] + bmu[0];
}

// pack weights: fp16 MFMA B-fragment order (B[k][n] = W[n][k]) for the
// f-net / wih / wl1; int8 B-fragment order (K=64) for Whh.
extern "C" __global__ void odernn_init(
    const float* __restrict__ W_ih, const float* __restrict__ W_hh,
    const float* __restrict__ W1,   const float* __restrict__ W2,
    const float* __restrict__ Wl1,
    _Float16* w1p, _Float16* w2p, signed char* whh8, _Float16* wih,
    _Float16* wl1p)
{
    const int idx = blockIdx.x * blockDim.x + threadIdx.x;
    const int stride = gridDim.x * blockDim.x;
    // W1: KT=16, NT=4 (N 50->64), K=512
    for (int p = idx; p < 32768; p += stride) {
        int j = p & 7, lane = (p >> 3) & 63, t = p >> 9;
        int nt = t & 3, kt = t >> 2;
        int n = nt*16 + (lane & 15), k = kt*32 + ((lane >> 4) << 3) + j;
        w1p[p] = (_Float16)((n < 50) ? W1[n*512 + k] : 0.f);
    }
    // W2: KT=2 (K 50->64), NT=32, N=512
    for (int p = idx; p < 32768; p += stride) {
        int j = p & 7, lane = (p >> 3) & 63, t = p >> 9;
        int nt = t & 31, kt = t >> 5;
        int n = nt*16 + (lane & 15), k = kt*32 + ((lane >> 4) << 3) + j;
        w2p[p] = (_Float16)((k < 50) ? W2[n*50 + k] : 0.f);
    }
    // Whh int8: KT=8 (K=64 each), NT=32; B frag: 16 bytes/lane,
    // n = nt*16+(lane&15), k = kt*64 + (lane>>4)*16 + j
    for (int p = idx; p < 262144; p += stride) {
        int j = p & 15, lane = (p >> 4) & 63, t = p >> 10;
        int nt = t & 31, kt = t >> 5;
        int n = nt*16 + (lane & 15), k = kt*64 + ((lane >> 4) << 4) + j;
        float v = rintf(W_hh[n*512 + k] * SB_WHH);
        v = fminf(127.0f, fmaxf(-127.0f, v));
        whh8[p] = (signed char)(int)v;
    }
    // Wih: KT=2, NT=32, K=64 (fp16)
    for (int p = idx; p < 32768; p += stride) {
        int j = p & 7, lane = (p >> 3) & 63, t = p >> 9;
        int nt = t & 31, kt = t >> 5;
        int n = nt*16 + (lane & 15), k = kt*32 + ((lane >> 4) << 3) + j;
        wih[p] = (_Float16)W_ih[n*64 + k];
    }
    // Wl1: KT=16, NT=16, N=256, K=512
    for (int p = idx; p < 131072; p += stride) {
        int j = p & 7, lane = (p >> 3) & 63, t = p >> 9;
        int nt = t & 15, kt = t >> 4;
        int n = nt*16 + (lane & 15), k = kt*32 + ((lane >> 4) << 3) + j;
        wl1p[p] = (_Float16)Wl1[n*512 + k];
    }
}

extern "C" void kernel_launch(void* const* d_in, const int* in_sizes, int n_in,
                              void* d_out, int out_size, void* d_ws, size_t ws_size,
                              hipStream_t stream)
{
    (void)in_sizes; (void)n_in; (void)out_size;
    const float* dt   = (const float*)d_in[0];
    const float* x    = (const float*)d_in[1];
    const float* W_ih = (const float*)d_in[2];
    const float* b_ih = (const float*)d_in[3];
    const float* W_hh = (const float*)d_in[4];
    const float* b_hh = (const float*)d_in[5];
    const float* W1   = (const float*)d_in[6];
    const float* b1   = (const float*)d_in[7];
    const float* W2   = (const float*)d_in[8];
    const float* b2   = (const float*)d_in[9];
    const float* Wl1  = (const float*)d_in[10];
    const float* bl1  = (const float*)d_in[11];
    const float* Wmu  = (const float*)d_in[12];
    const float* bmu  = (const float*)d_in[13];
    float* out = (float*)d_out;

    char* ws = (char*)d_ws;
    _Float16*    w1p  = (_Float16*)(ws);             // 64 KB
    _Float16*    w2p  = (_Float16*)(ws + 65536);     // 64 KB
    signed char* whh8 = (signed char*)(ws + 131072); // 256 KB (of 512 KB slot)
    _Float16*    wih  = (_Float16*)(ws + 655360);    // 64 KB
    _Float16*    wl1p = (_Float16*)(ws + 720896);    // 256 KB
    _Float16*    yg   = (_Float16*)(ws + 1048576);   // 105 MB (if available)

    const size_t need = 1048576 + (size_t)1024 * Tn * 512 * sizeof(_Float16);
    const int defer = (ws_size >= need) ? 1 : 0;

    odernn_init<<<256, 256, 0, stream>>>(W_ih, W_hh, W1, W2, Wl1,
                                         w1p, w2p, whh8, wih, wl1p);
    odernn_main<<<NWG, NTHR, 0, stream>>>(dt, x, b_ih, b_hh, b1, b2, bl1, Wmu, bmu,
                                          w1p, w2p, whh8, wih, wl1p,
                                          yg, out, defer);
    if (defer)
        odernn_head<<<(1024/16)*Tn, 256, 0, stream>>>(yg, wl1p, bl1, Wmu, bmu, out);
}

// Round 12
// 628.022 us; speedup vs baseline: 2.0867x; 1.1530x over previous
//
#include <hip/hip_runtime.h>
#include <math.h>

// ODE-RNN persistent kernel, round 23: spread elementwise work over all lanes.
// R22 post-mortem: AGPR residency passed (absmax 0.00208) but dur == R19
// (587us) -- the Whh L2 stream was ALREADY hidden under MFMA+TLP; the real
// binder is VALU issue (VALUBusy 56%): dequant/tanh/quant, GEMM2-tanh and
// Euler update all ran in lanes<16, 8-deep (3/4 of issue slots masked).
// R23: producers dump RAW accumulators to LDS qraw; two spread passes use
// all 1024 threads x 2 values (dequant pass after S1; Euler pass after new
// S4b, with the yg store FUSED -- value already in regs). b2 staged in LDS.
// tanh uses v_rcp_f32 (rel err 1e-6, exact 0 at 0). Everything else = R22
// (AGPR Whh via atomic asm load block, LDS f-net, int8 MFMA, 256 WGs).
// LDS 161.9 KB <= 160 KiB cap. 6 barriers/step (was 5).

#define NWG  256
#define NTHR 1024
#define Tn   100
#define Dn   64
#define Hn   512
#define Fn   50
#define YP   528   // fp16 pitch
#define YQP  544   // i8 pitch
#define XP   80
#define GPp  80
#define GPI  17
#define BXP  516   // bcx pitch (dwords)
#define QRP  516   // qraw pitch (dwords)
#define SB_WHH 2873.682f              // 127 / (1/sqrt(512))
#define QDH (1.0f/(125.0f*SB_WHH))    // dequant: (1/sA)*(1/sB)

typedef __attribute__((ext_vector_type(8))) _Float16 half8;
typedef __attribute__((ext_vector_type(2))) _Float16 half2v;
typedef __attribute__((ext_vector_type(4))) float f32x4;
typedef __attribute__((ext_vector_type(2))) float f32x2;
typedef __attribute__((ext_vector_type(4))) int   i32x4;

__device__ __forceinline__ float my_tanh(float v) {
    float e = __expf(2.0f * v);
    return 1.0f - 2.0f * __builtin_amdgcn_rcpf(e + 1.0f);   // exact 0 at v=0
}
__device__ __forceinline__ float wave_red(float v) {
#pragma unroll
    for (int o = 32; o > 0; o >>= 1) v += __shfl_down(v, o);
    return v;
}
__device__ __forceinline__ signed char q125(float v) {
    return (signed char)(int)rintf(v * 125.0f);
}

// f-net through GEMM2, writing RAW GEMM2 accumulators to qraw (no tanh --
// the spread Euler pass finishes). Two internal syncs (S3, S4).
__device__ __forceinline__ void feval_raw(
    const _Float16* arg, const half8* w1b, const half8* w2b,
    float* gp, _Float16* gbf, float* qraw, const float b1v,
    int w, int lane, int tid, const int ci0, const int ci1)
{
    const int m4 = lane & 3, q = (lane >> 4) & 3;
    const int kh = w >> 2;
    f32x4 acc = {0.f, 0.f, 0.f, 0.f};
    const _Float16* arow = arg + m4 * YP + q * 8;
#pragma unroll
    for (int t = 0; t < 4; ++t) {
        half8 a = *(const half8*)(arow + (kh * 4 + t) * 32);
        acc = __builtin_amdgcn_mfma_f32_16x16x32_f16(a, w1b[t * 64], acc, 0, 0, 0);
    }
    if (lane < 16) {
#pragma unroll
        for (int r = 0; r < 4; ++r)
            gp[(w * 4 + r) * GPI + lane] = acc[r];
    }
    __syncthreads();   // S3
    if (tid < 256) {   // mid layer once: 4 rows x 64 neurons
        const int r = tid >> 6, n = tid & 63;
        const int nt = n >> 4, c = n & 15;
        float s = gp[((0*4 + nt) * 4 + r) * GPI + c]
                + gp[((1*4 + nt) * 4 + r) * GPI + c]
                + gp[((2*4 + nt) * 4 + r) * GPI + c]
                + gp[((3*4 + nt) * 4 + r) * GPI + c];
        float g = (n < Fn) ? my_tanh(s + b1v) : 0.0f;
        gbf[r * GPp + n] = (_Float16)g;
    }
    __syncthreads();   // S4
    half8 af0 = *(const half8*)(gbf + m4 * GPp + q * 8);
    half8 af1 = *(const half8*)(gbf + m4 * GPp + 32 + q * 8);
#pragma unroll
    for (int i = 0; i < 2; ++i) {
        f32x4 c = {0.f, 0.f, 0.f, 0.f};
        c = __builtin_amdgcn_mfma_f32_16x16x32_f16(af0, w2b[(i*2 + 0) * 64], c, 0, 0, 0);
        c = __builtin_amdgcn_mfma_f32_16x16x32_f16(af1, w2b[(i*2 + 1) * 64], c, 0, 0, 0);
        if (lane < 16) {
            const int ci = (i == 0) ? ci0 : ci1;
#pragma unroll
            for (int r = 0; r < 4; ++r)
                qraw[r * QRP + ci] = c[r];
        }
    }
}

extern "C" __global__ void __launch_bounds__(NTHR, 4)
odernn_main(const float* __restrict__ dt, const float* __restrict__ x,
            const float* __restrict__ b_ih, const float* __restrict__ b_hh,
            const float* __restrict__ b1,   const float* __restrict__ b2,
            const float* __restrict__ bl1,  const float* __restrict__ Wmu,
            const float* __restrict__ bmu,
            const _Float16* __restrict__ w1p,  const _Float16* __restrict__ w2p,
            const signed char* __restrict__ whh8, const _Float16* __restrict__ wih,
            const _Float16* __restrict__ wl1p,
            _Float16* __restrict__ yg, float* __restrict__ out, int defer)
{
    __shared__ __align__(16) _Float16 ybuf[4*YP];
    __shared__ __align__(16) signed char ybq[4*YQP];
    __shared__ __align__(16) _Float16 xbuf[4*XP];
    __shared__ __align__(16) _Float16 gbf[4*GPp];
    __shared__ __align__(16) float    gp[64*GPI];
    __shared__ __align__(16) float    bcx[4*BXP];
    __shared__ __align__(16) float    qraw[4*QRP];
    __shared__ __align__(16) float    b2L[512];
    __shared__ float sc_row[4], hp[64];
    __shared__ __align__(16) _Float16 w1L[16 * 4 * 64 * 8];   // 64 KB
    __shared__ __align__(16) _Float16 w2L[16 * 4 * 64 * 8];   // 64 KB

    const int tid  = threadIdx.x;
    const int w    = tid >> 6;       // wave 0..15
    const int lane = tid & 63;
    const int m4   = lane & 3, q = (lane >> 4) & 3;
    const int cw   = lane & 15;
    const int row0 = blockIdx.x * 4;
    // spread-pass coordinates: thread handles values (vr, vn) and (vr, vn+1)
    const int vr = (tid * 2) >> 9, vn = (tid * 2) & 511;

    for (int i = tid; i < 4*YP;  i += NTHR) ybuf[i] = (_Float16)0.0f;
    for (int i = tid; i < 4*YQP; i += NTHR) ybq[i]  = 0;
    if (tid < 512) b2L[tid] = b2[tid];

    // stage loop-invariant f-net fragments into LDS (once; R19-proven)
    {
        half8* w1d = ((half8*)w1L) + (w * 4) * 64 + lane;
        const int kh = w >> 2, nt1 = w & 3;
#pragma unroll
        for (int t = 0; t < 4; ++t) {
            const int kt = kh * 4 + t;
            w1d[t * 64] = ((const half8*)w1p)[(((kt << 2) + nt1) << 6) + lane];
        }
        half8* w2d = ((half8*)w2L) + (w * 4) * 64 + lane;
#pragma unroll
        for (int i = 0; i < 2; ++i) {
            const int nt = w + (i << 4);
            w2d[(i*2 + 0) * 64] = ((const half8*)w2p)[(nt << 6) + lane];
            w2d[(i*2 + 1) * 64] = ((const half8*)w2p)[((32 + nt) << 6) + lane];
        }
    }

    // ---- Whh int8 B-fragments -> AGPRs in ONE atomic asm block (R22-proven)
    i32x4 bq0,  bq1,  bq2,  bq3,  bq4,  bq5,  bq6,  bq7;
    i32x4 bq8,  bq9,  bq10, bq11, bq12, bq13, bq14, bq15;
#define WADDR(kt, ntadd) (whh8 + ((((kt)*32 + w + (ntadd)) << 10) + (lane << 4)))
    asm volatile(
        "global_load_dwordx4 %0, %16, off\n\t"
        "global_load_dwordx4 %1, %17, off\n\t"
        "global_load_dwordx4 %2, %18, off\n\t"
        "global_load_dwordx4 %3, %19, off\n\t"
        "global_load_dwordx4 %4, %20, off\n\t"
        "global_load_dwordx4 %5, %21, off\n\t"
        "global_load_dwordx4 %6, %22, off\n\t"
        "global_load_dwordx4 %7, %23, off\n\t"
        "global_load_dwordx4 %8, %24, off\n\t"
        "global_load_dwordx4 %9, %25, off\n\t"
        "global_load_dwordx4 %10, %26, off\n\t"
        "global_load_dwordx4 %11, %27, off\n\t"
        "global_load_dwordx4 %12, %28, off\n\t"
        "global_load_dwordx4 %13, %29, off\n\t"
        "global_load_dwordx4 %14, %30, off\n\t"
        "global_load_dwordx4 %15, %31, off\n\t"
        "s_waitcnt vmcnt(0)"
        : "=a"(bq0),  "=a"(bq1),  "=a"(bq2),  "=a"(bq3),
          "=a"(bq4),  "=a"(bq5),  "=a"(bq6),  "=a"(bq7),
          "=a"(bq8),  "=a"(bq9),  "=a"(bq10), "=a"(bq11),
          "=a"(bq12), "=a"(bq13), "=a"(bq14), "=a"(bq15)
        : "v"(WADDR(0,0)),  "v"(WADDR(0,16)),
          "v"(WADDR(1,0)),  "v"(WADDR(1,16)),
          "v"(WADDR(2,0)),  "v"(WADDR(2,16)),
          "v"(WADDR(3,0)),  "v"(WADDR(3,16)),
          "v"(WADDR(4,0)),  "v"(WADDR(4,16)),
          "v"(WADDR(5,0)),  "v"(WADDR(5,16)),
          "v"(WADDR(6,0)),  "v"(WADDR(6,16)),
          "v"(WADDR(7,0)),  "v"(WADDR(7,16))
        : "memory");
#undef WADDR

    float bC[2];
    int ci[2];
#pragma unroll
    for (int i = 0; i < 2; ++i) {
        const int n = (w + i*16)*16 + cw;
        bC[i] = b_ih[n] + b_hh[n];
        ci[i] = n;
    }
    const float b1v = (tid < 256 && (tid & 63) < Fn) ? b1[tid & 63] : 0.0f;
    const float blv = bl1[w*16 + cw];   // fallback head only
    const float wmv = Wmu[w*16 + cw];
    const float bmu0 = bmu[0];

    const half8* w1b = ((const half8*)w1L) + (w * 4) * 64 + lane;
    const half8* w2b = ((const half8*)w2L) + (w * 4) * 64 + lane;

    float xv = 0.f, scn = 0.f;

    // stage x/sc for ts = 0
    if (tid < 256) {
        const int r = tid >> 6, c = tid & 63;
        xbuf[r*XP + c] = (_Float16)x[((size_t)(row0 + r)*Tn + 0)*Dn + c];
    }
    if (tid < 4) {
        const size_t di = ((size_t)(row0 + tid)*Tn + 0)*2;
        sc_row[tid] = (dt[di + 1] - dt[di]) * 0.01f;
    }
    __syncthreads();

#pragma unroll 1
    for (int ts = 0; ts < Tn; ++ts) {
        // ---- Phase A: x@Wih (fp16 MFMA) + bias -> LDS bcx; accX dies here ----
        {
            f32x4 accX0 = {0.f,0.f,0.f,0.f};
            f32x4 accX1 = {0.f,0.f,0.f,0.f};
            const _Float16* xh = xbuf + m4*XP + q*8;
#pragma unroll
            for (int kt = 0; kt < 2; ++kt) {
                half8 ah = *(const half8*)(xh + kt*32);
                half8 bw0 = *(const half8*)(wih + (((kt*32 + w)      << 9) + (lane << 3)));
                half8 bw1 = *(const half8*)(wih + (((kt*32 + w + 16) << 9) + (lane << 3)));
                accX0 = __builtin_amdgcn_mfma_f32_16x16x32_f16(ah, bw0, accX0, 0,0,0);
                accX1 = __builtin_amdgcn_mfma_f32_16x16x32_f16(ah, bw1, accX1, 0,0,0);
            }
            if (lane < 16) {
#pragma unroll
                for (int r = 0; r < 4; ++r) {
                    bcx[r*BXP + ci[0]] = accX0[r] + bC[0];
                    bcx[r*BXP + ci[1]] = accX1[r] + bC[1];
                }
            }
        }
        __builtin_amdgcn_sched_barrier(0);   // pin phase: accX must die here

        // ---- Phase B: h@Whh int8 MFMA, B from AGPRs; dump RAW accQ -> qraw ----
        {
            i32x4 accQ0 = {0,0,0,0};
            i32x4 accQ1 = {0,0,0,0};
            const signed char* yq = ybq + m4*YQP + q*16;
            i32x4 aq;
#define QMM(kt, B0, B1, PRE, POST) { \
            aq = *(const i32x4*)(yq + (kt)*64); \
            asm(PRE \
                "v_mfma_i32_16x16x64_i8 %0, %2, %3, %0\n\t" \
                "v_mfma_i32_16x16x64_i8 %1, %2, %4, %1" \
                POST \
                : "+v"(accQ0), "+v"(accQ1) \
                : "v"(aq), "a"(B0), "a"(B1)); }
            QMM(0, bq0,  bq1,  "s_nop 3\n\t", "")
            QMM(1, bq2,  bq3,  "", "")
            QMM(2, bq4,  bq5,  "", "")
            QMM(3, bq6,  bq7,  "", "")
            QMM(4, bq8,  bq9,  "", "")
            QMM(5, bq10, bq11, "", "")
            QMM(6, bq12, bq13, "", "")
            QMM(7, bq14, bq15, "", "\n\ts_nop 7\n\ts_nop 7\n\ts_nop 7")
#undef QMM
            if (lane < 16) {
#pragma unroll
                for (int r = 0; r < 4; ++r) {
                    qraw[r*QRP + ci[0]] = (float)accQ0[r];
                    qraw[r*QRP + ci[1]] = (float)accQ1[r];
                }
            }
        }
        __syncthreads();   // S1: qraw + bcx visible; old ybq/xbuf reads done

        // capture this thread's row scale (stable until the pre-S5 update)
        const float myscr = sc_row[vr];

        // ---- spread pass 1: dequant + tanh + quant, 1024 thr x 2 values ----
        {
            f32x2 qr = *(const f32x2*)(qraw + vr*QRP + vn);
            f32x2 bx = *(const f32x2*)(bcx  + vr*BXP + vn);
            float y0a = my_tanh(qr[0]*QDH + bx[0]);
            float y0b = my_tanh(qr[1]*QDH + bx[1]);
            half2v ho; ho[0] = (_Float16)y0a; ho[1] = (_Float16)y0b;
            *(half2v*)(ybuf + vr*YP + vn) = ho;
            ybq[vr*YQP + vn]     = q125(y0a);
            ybq[vr*YQP + vn + 1] = q125(y0b);
        }
        // prefetch x/dt for next step (lands during feval)
        {
            const int tsn = (ts + 1 < Tn) ? ts + 1 : ts;
            if (tid < 256) {
                const int r = tid >> 6, c = tid & 63;
                xv = x[((size_t)(row0 + r)*Tn + tsn)*Dn + c];
            }
            if (tid < 4) {
                const size_t di = ((size_t)(row0 + tid)*Tn + tsn)*2;
                scn = (dt[di + 1] - dt[di]) * 0.01f;
            }
        }
        __syncthreads();   // S2: y0 visible in ybuf

        // ---- ODE f-eval through raw GEMM2 (S3, S4 inside) ----
        feval_raw(ybuf, w1b, w2b, gp, gbf, qraw, b1v, w, lane, tid, ci[0], ci[1]);
        __syncthreads();   // S4b: raw GEMM2 accs in qraw visible

        // ---- spread pass 2: tanh + Euler + quant (+ fused yg store) ----
        {
            f32x2 qr = *(const f32x2*)(qraw + vr*QRP + vn);
            float k0 = my_tanh(qr[0] + b2L[vn])     * myscr;
            float k1 = my_tanh(qr[1] + b2L[vn + 1]) * myscr;
            half2v hv = *(const half2v*)(ybuf + vr*YP + vn);
            float yn0 = (float)hv[0] + k0;
            float yn1 = (float)hv[1] + k1;
            half2v ho; ho[0] = (_Float16)yn0; ho[1] = (_Float16)yn1;
            *(half2v*)(ybuf + vr*YP + vn) = ho;
            ybq[vr*YQP + vn]     = q125(yn0);
            ybq[vr*YQP + vn + 1] = q125(yn1);
            if (defer)
                *(half2v*)(yg + (((size_t)(row0 + vr)*Tn + ts)*512 + vn)) = ho;
        }
        if (tid < 256) xbuf[(tid >> 6)*XP + (tid & 63)] = (_Float16)xv;
        if (tid < 4)   sc_row[tid] = scn;
        __syncthreads();   // S5: ynew + x + sc visible

        if (!defer) {
            // in-loop head (fallback)
            f32x4 aH = {0.f,0.f,0.f,0.f};
            const _Float16* yh = ybuf + m4*YP + q*8;
#pragma unroll 4
            for (int kt = 0; kt < 16; ++kt) {
                half8 ah = *(const half8*)(yh + kt*32);
                half8 b = *(const half8*)(wl1p + ((kt*16 + w) << 9) + (lane << 3));
                aH = __builtin_amdgcn_mfma_f32_16x16x32_f16(ah, b, aH, 0,0,0);
            }
            float pr[4];
#pragma unroll
            for (int r = 0; r < 4; ++r) {
                float p = (lane < 16) ? fmaxf(aH[r] + blv, 0.0f) * wmv : 0.0f;
                pr[r] = wave_red(p);
            }
            if (lane == 0) {
#pragma unroll
                for (int r = 0; r < 4; ++r) hp[w*4 + r] = pr[r];
            }
            __syncthreads();
            if (tid < 4) {
                float s = bmu0;
#pragma unroll
                for (int wv = 0; wv < 16; ++wv) s += hp[wv*4 + tid];
                out[(size_t)(row0 + tid)*Tn + ts] = s;
            }
            __syncthreads();
        }
    }
}

// phase-2 head: out[b,t] = relu(y[b,t]@Wl1^T + bl1)@Wmu^T + bmu
// grid = (B/16)*Tn WGs x 256 threads; wave w covers n in [w*64,(w+1)*64)
extern "C" __global__ void __launch_bounds__(256, 4)
odernn_head(const _Float16* __restrict__ yg, const _Float16* __restrict__ wl1p,
            const float* __restrict__ bl1, const float* __restrict__ Wmu,
            const float* __restrict__ bmu, float* __restrict__ out)
{
    __shared__ float hp[4][16];
    const int tid = threadIdx.x, w = tid >> 6, lane = tid & 63;
    const int q = (lane >> 4) & 3;
    const int b0 = (blockIdx.x / Tn) * 16, ts = blockIdx.x % Tn;

    f32x4 acc[4];
#pragma unroll
    for (int j = 0; j < 4; ++j) acc[j] = (f32x4){0.f,0.f,0.f,0.f};
    const _Float16* ap = yg + ((size_t)(b0 + (lane & 15))*Tn + ts)*512 + q*8;
#pragma unroll 4
    for (int kt = 0; kt < 16; ++kt) {
        half8 a = *(const half8*)(ap + kt*32);
#pragma unroll
        for (int j = 0; j < 4; ++j) {
            half8 b = *(const half8*)(wl1p + ((kt*16 + w*4 + j) << 9) + (lane << 3));
            acc[j] = __builtin_amdgcn_mfma_f32_16x16x32_f16(a, b, acc[j], 0,0,0);
        }
    }
    float pr[4] = {0.f, 0.f, 0.f, 0.f};
#pragma unroll
    for (int j = 0; j < 4; ++j) {
        const int n = (w*4 + j)*16 + (lane & 15);
        const float blv = bl1[n], wmv = Wmu[n];
#pragma unroll
        for (int r = 0; r < 4; ++r)
            pr[r] += fmaxf(acc[j][r] + blv, 0.0f) * wmv;
    }
#pragma unroll
    for (int r = 0; r < 4; ++r)
#pragma unroll
        for (int o = 1; o < 16; o <<= 1) pr[r] += __shfl_xor(pr[r], o);
    if ((lane & 15) == 0) {
        const int g = lane >> 4;
#pragma unroll
        for (int r = 0; r < 4; ++r) hp[w][g*4 + r] = pr[r];
    }
    __syncthreads();
    if (tid < 16)
        out[(size_t)(b0 + tid)*Tn + ts] =
            hp[0][tid] + hp[1][tid] + hp[2][tid] + hp[3][tid] + bmu[0];
}

// pack weights: fp16 MFMA B-fragment order (B[k][n] = W[n][k]) for the
// f-net / wih / wl1; int8 B-fragment order (K=64) for Whh.
extern "C" __global__ void odernn_init(
    const float* __restrict__ W_ih, const float* __restrict__ W_hh,
    const float* __restrict__ W1,   const float* __restrict__ W2,
    const float* __restrict__ Wl1,
    _Float16* w1p, _Float16* w2p, signed char* whh8, _Float16* wih,
    _Float16* wl1p)
{
    const int idx = blockIdx.x * blockDim.x + threadIdx.x;
    const int stride = gridDim.x * blockDim.x;
    // W1: KT=16, NT=4 (N 50->64), K=512
    for (int p = idx; p < 32768; p += stride) {
        int j = p & 7, lane = (p >> 3) & 63, t = p >> 9;
        int nt = t & 3, kt = t >> 2;
        int n = nt*16 + (lane & 15), k = kt*32 + ((lane >> 4) << 3) + j;
        w1p[p] = (_Float16)((n < 50) ? W1[n*512 + k] : 0.f);
    }
    // W2: KT=2 (K 50->64), NT=32, N=512
    for (int p = idx; p < 32768; p += stride) {
        int j = p & 7, lane = (p >> 3) & 63, t = p >> 9;
        int nt = t & 31, kt = t >> 5;
        int n = nt*16 + (lane & 15), k = kt*32 + ((lane >> 4) << 3) + j;
        w2p[p] = (_Float16)((k < 50) ? W2[n*50 + k] : 0.f);
    }
    // Whh int8: KT=8 (K=64 each), NT=32; B frag: 16 bytes/lane,
    // n = nt*16+(lane&15), k = kt*64 + (lane>>4)*16 + j
    for (int p = idx; p < 262144; p += stride) {
        int j = p & 15, lane = (p >> 4) & 63, t = p >> 10;
        int nt = t & 31, kt = t >> 5;
        int n = nt*16 + (lane & 15), k = kt*64 + ((lane >> 4) << 4) + j;
        float v = rintf(W_hh[n*512 + k] * SB_WHH);
        v = fminf(127.0f, fmaxf(-127.0f, v));
        whh8[p] = (signed char)(int)v;
    }
    // Wih: KT=2, NT=32, K=64 (fp16)
    for (int p = idx; p < 32768; p += stride) {
        int j = p & 7, lane = (p >> 3) & 63, t = p >> 9;
        int nt = t & 31, kt = t >> 5;
        int n = nt*16 + (lane & 15), k = kt*32 + ((lane >> 4) << 3) + j;
        wih[p] = (_Float16)W_ih[n*64 + k];
    }
    // Wl1: KT=16, NT=16, N=256, K=512
    for (int p = idx; p < 131072; p += stride) {
        int j = p & 7, lane = (p >> 3) & 63, t = p >> 9;
        int nt = t & 15, kt = t >> 4;
        int n = nt*16 + (lane & 15), k = kt*32 + ((lane >> 4) << 3) + j;
        wl1p[p] = (_Float16)Wl1[n*512 + k];
    }
}

extern "C" void kernel_launch(void* const* d_in, const int* in_sizes, int n_in,
                              void* d_out, int out_size, void* d_ws, size_t ws_size,
                              hipStream_t stream)
{
    (void)in_sizes; (void)n_in; (void)out_size;
    const float* dt   = (const float*)d_in[0];
    const float* x    = (const float*)d_in[1];
    const float* W_ih = (const float*)d_in[2];
    const float* b_ih = (const float*)d_in[3];
    const float* W_hh = (const float*)d_in[4];
    const float* b_hh = (const float*)d_in[5];
    const float* W1   = (const float*)d_in[6];
    const float* b1   = (const float*)d_in[7];
    const float* W2   = (const float*)d_in[8];
    const float* b2   = (const float*)d_in[9];
    const float* Wl1  = (const float*)d_in[10];
    const float* bl1  = (const float*)d_in[11];
    const float* Wmu  = (const float*)d_in[12];
    const float* bmu  = (const float*)d_in[13];
    float* out = (float*)d_out;

    char* ws = (char*)d_ws;
    _Float16*    w1p  = (_Float16*)(ws);             // 64 KB
    _Float16*    w2p  = (_Float16*)(ws + 65536);     // 64 KB
    signed char* whh8 = (signed char*)(ws + 131072); // 256 KB (of 512 KB slot)
    _Float16*    wih  = (_Float16*)(ws + 655360);    // 64 KB
    _Float16*    wl1p = (_Float16*)(ws + 720896);    // 256 KB
    _Float16*    yg   = (_Float16*)(ws + 1048576);   // 105 MB (if available)

    const size_t need = 1048576 + (size_t)1024 * Tn * 512 * sizeof(_Float16);
    const int defer = (ws_size >= need) ? 1 : 0;

    odernn_init<<<256, 256, 0, stream>>>(W_ih, W_hh, W1, W2, Wl1,
                                         w1p, w2p, whh8, wih, wl1p);
    odernn_main<<<NWG, NTHR, 0, stream>>>(dt, x, b_ih, b_hh, b1, b2, bl1, Wmu, bmu,
                                          w1p, w2p, whh8, wih, wl1p,
                                          yg, out, defer);
    if (defer)
        odernn_head<<<(1024/16)*Tn, 256, 0, stream>>>(yg, wl1p, bl1, Wmu, bmu, out);
}